// Round 8
// baseline (817.273 us; speedup 1.0000x reference)
//
#include <hip/hip_runtime.h>
#include <hip/hip_fp8.h>
#include <stdint.h>

// ---------------------------------------------------------------------------
// VQ-VAE quantizer. Coarse: MX-fp8 mfma_scale_f32_16x16x128, 256x256 tile,
// 8 waves, BK=128. R8: B-only LDS dbuf (64KB -> 2 blocks/CU), A direct
// global->VGPR (no LDS for A). R7's pinned gload_lds schedule retained.
// Sizes: M=B*T=16384, D=1024, K=8192 codes, H=512.
// ---------------------------------------------------------------------------

#define MROWS  16384
#define DDIM   1024
#define KCODES 8192
#define HDIM   512

typedef __attribute__((ext_vector_type(4))) float  f32x4;
typedef __attribute__((ext_vector_type(8))) __bf16 bf16x8;
typedef __attribute__((ext_vector_type(4))) int    i32x4;
typedef __attribute__((ext_vector_type(8))) int    i32x8;

__device__ __forceinline__ unsigned short f2bf(float f) {
  uint32_t b = __float_as_uint(f);
  b += 0x7FFFu + ((b >> 16) & 1u);          // RNE
  return (unsigned short)(b >> 16);
}

__device__ __forceinline__ uint32_t f2fp8(float f) {
  return (uint32_t)__hip_fp8_e4m3(f).__x;   // OCP e4m3fn, saturating
}

__device__ __forceinline__ void gload_lds16(const void* g, void* l) {
  __builtin_amdgcn_global_load_lds(
      (__attribute__((address_space(1))) void*)(uintptr_t)g,
      (__attribute__((address_space(3))) void*)(uint32_t)(uintptr_t)l,
      16, 0, 0);
}

__device__ __forceinline__ f32x4 mfma_mx(i32x8 a, i32x8 b, f32x4 c) {
  // cbsz=0 (A=fp8 e4m3), blgp=0 (B=fp8); scales: every byte 127 -> 2^0
  return __builtin_amdgcn_mfma_scale_f32_16x16x128_f8f6f4(
      a, b, c, 0, 0, 0, 0x7F7F7F7F, 0, 0x7F7F7F7F);
}

__device__ __forceinline__ float waveReduceSum(float v) {
#pragma unroll
  for (int off = 32; off > 0; off >>= 1) v += __shfl_xor(v, off, 64);
  return v;
}

// ---------------------------------------------------------------------------
// K1: features f32 -> fp8 e4m3 (8 elems/thread)
// ---------------------------------------------------------------------------
__global__ __launch_bounds__(256) void cvt_x_kernel(
    const float* __restrict__ in, uint8_t* __restrict__ q8, int n8) {
  const int id = blockIdx.x * 256 + threadIdx.x;
  if (id >= n8) return;
  const float4 v0 = ((const float4*)in)[id * 2];
  const float4 v1 = ((const float4*)in)[id * 2 + 1];
  uint32_t a = f2fp8(v0.x) | (f2fp8(v0.y) << 8) | (f2fp8(v0.z) << 16) |
               (f2fp8(v0.w) << 24);
  uint32_t b = f2fp8(v1.x) | (f2fp8(v1.y) << 8) | (f2fp8(v1.z) << 16) |
               (f2fp8(v1.w) << 24);
  uint2 u; u.x = a; u.y = b;
  ((uint2*)q8)[id] = u;
}

// ---------------------------------------------------------------------------
// K2: codebook f32 -> {bf16 (decoder GEMM), fp8 (coarse)} + norm cn[k]
// ---------------------------------------------------------------------------
__global__ __launch_bounds__(256) void cvt_cb_cn_kernel(
    const float* __restrict__ cb, unsigned short* __restrict__ obf,
    uint8_t* __restrict__ q8, float* __restrict__ cn) {
  __shared__ float wsum[4];
  const int k = blockIdx.x, t = threadIdx.x;
  const float4 v = ((const float4*)(cb + (size_t)k * DDIM))[t];
  ushort4 u;
  u.x = f2bf(v.x); u.y = f2bf(v.y); u.z = f2bf(v.z); u.w = f2bf(v.w);
  ((ushort4*)(obf + (size_t)k * DDIM))[t] = u;
  const uint32_t p8 = f2fp8(v.x) | (f2fp8(v.y) << 8) | (f2fp8(v.z) << 16) |
                      (f2fp8(v.w) << 24);
  ((uint32_t*)(q8 + (size_t)k * DDIM))[t] = p8;
  float p = v.x * v.x + v.y * v.y + v.z * v.z + v.w * v.w;
  p = waveReduceSum(p);
  if ((t & 63) == 0) wsum[t >> 6] = p;
  __syncthreads();
  if (t == 0) cn[k] = wsum[0] + wsum[1] + wsum[2] + wsum[3];
}

// ---------------------------------------------------------------------------
// K3: weight transpose f32 [R][C] -> bf16 [C][R]
// ---------------------------------------------------------------------------
__global__ __launch_bounds__(256) void transpose_w_kernel(
    const float* __restrict__ w, unsigned short* __restrict__ wt, int R, int C) {
  const int id = blockIdx.x * 256 + threadIdx.x;
  if (id >= R * C) return;
  const int c = id / R, r = id % R;
  wt[id] = f2bf(w[(size_t)r * C + c]);
}

// ---------------------------------------------------------------------------
// K4: coarse scores = cn[k] - 2 * (xq . cq) via MX-fp8 MFMA (K=128).
// 256 rows x 256 codes per block, 8 waves (wm 0..1 x wn 0..3), 8 K-tiles.
// B in LDS dbuf 2x32KB (XOR swizzle byte^=((row&7)<<4), pre-swizzled global
// source, pinned STAGE schedule = R7). A direct global->VGPR (rows shared by
// the 4 wn-waves -> L1 reuse); 16 dwordx4/wave/KT in two 4-frag batches.
// Fold: per-row top-2 over 256 cols -> cand2[row][nb] (nb 0..31).
// ---------------------------------------------------------------------------
__global__ __launch_bounds__(512, 2) void coarse_kernel(
    const uint8_t* __restrict__ xq,   // [MROWS][DDIM] fp8
    const uint8_t* __restrict__ cq,   // [KCODES][DDIM] fp8
    const float* __restrict__ cn,     // [KCODES]
    uint32_t* __restrict__ cand2)     // [MROWS][32][4]
{
  __shared__ char smem[65536];   // B dbuf 2x32KB; fold scratch aliased

  const int tid = threadIdx.x;
  const int l = tid & 63, w = tid >> 6;
  const int lr = l & 15, lg = l >> 4;
  const int wm = w >> 2, wn = w & 3;

  // bijective XCD swizzle (nwg = 2048 = 8 * 256)
  const int bid = blockIdx.x;
  const int swz = (bid & 7) * 256 + (bid >> 3);
  const int mb = swz >> 5, nb = swz & 31;
  const int r0 = mb * 256, c0 = nb * 256;

  // B staging: linear LDS dest tid*16 (+j*8192); chunk holds global
  // row = (tid>>3)+j*64, col byte = ((tid&7)*16) ^ ((row&7)<<4)
  const int srow = tid >> 3;                                   // 0..63
  const int scolb = ((tid & 7) * 16) ^ (((tid >> 3) & 7) << 4);
  const uint8_t* bSrc = cq + (size_t)(c0 + srow) * DDIM + scolb;
  const int dBase = tid * 16;

  // B fragment ds_read offsets (row&7 == lr&7)
  const int sxor = (lr & 7) << 4;
  const int kLo = (lg * 32) ^ sxor;
  const int kHi = (lg * 32 + 16) ^ sxor;
  const int bRow = (wn * 64 + lr) * 128;            // + ni*2048 + buf*32768

  // A direct-load base: row (r0 + wm*128 + mi*16 + lr), byte lg*32 + kt*128
  const uint8_t* aBase = xq + (size_t)(r0 + wm * 128 + lr) * DDIM + lg * 32;

#define STAGE_B(KT, BUF)                                                      \
  {                                                                           \
    char* sb = smem + (BUF) * 32768;                                          \
    _Pragma("unroll")                                                         \
    for (int j = 0; j < 4; ++j)                                               \
      gload_lds16(bSrc + (size_t)j * 65536 + (KT) * 128,                      \
                  sb + dBase + j * 8192);                                     \
  }

#define LDB(dst, off)                                                         \
  {                                                                           \
    i32x4 _lo = *(const i32x4*)(bb + (off) + kLo);                            \
    i32x4 _hi = *(const i32x4*)(bb + (off) + kHi);                            \
    dst = __builtin_shufflevector(_lo, _hi, 0, 1, 2, 3, 4, 5, 6, 7);          \
  }

#define LDA(dst, ptr)                                                         \
  {                                                                           \
    i32x4 _lo = *(const i32x4*)(ptr);                                         \
    i32x4 _hi = *(const i32x4*)((ptr) + 16);                                  \
    dst = __builtin_shufflevector(_lo, _hi, 0, 1, 2, 3, 4, 5, 6, 7);          \
  }

  f32x4 acc[8][4];
#pragma unroll
  for (int mi = 0; mi < 8; ++mi)
#pragma unroll
    for (int ni = 0; ni < 4; ++ni) acc[mi][ni] = 0.0f;

  // prologue: stage B kt0 -> buf0, kt1 -> buf1 (pinned)
  __builtin_amdgcn_sched_barrier(0);
  STAGE_B(0, 0)
  STAGE_B(1, 1)
  __builtin_amdgcn_sched_barrier(0);
  __syncthreads();                         // drains vmcnt(0): kt0+kt1 landed

#pragma unroll 1
  for (int kt = 0; kt < 8; ++kt) {
    const char* bb = smem + (kt & 1) * 32768;
    const uint8_t* aPtr = aBase + kt * 128;
    i32x8 afA[4], afB[4], bf[4];
#pragma unroll
    for (int mi = 0; mi < 4; ++mi) LDA(afA[mi], aPtr + (size_t)mi * 16384)
#pragma unroll
    for (int ni = 0; ni < 4; ++ni) LDB(bf[ni], bRow + ni * 2048)
#pragma unroll
    for (int mi = 0; mi < 4; ++mi)
      LDA(afB[mi], aPtr + (size_t)(mi + 4) * 16384)
    __builtin_amdgcn_s_setprio(1);
#pragma unroll
    for (int mi = 0; mi < 4; ++mi)
#pragma unroll
      for (int ni = 0; ni < 4; ++ni)
        acc[mi][ni] = mfma_mx(afA[mi], bf[ni], acc[mi][ni]);
    __builtin_amdgcn_s_setprio(0);
    __builtin_amdgcn_s_setprio(1);
#pragma unroll
    for (int mi = 0; mi < 4; ++mi)
#pragma unroll
      for (int ni = 0; ni < 4; ++ni)
        acc[mi + 4][ni] = mfma_mx(afB[mi], bf[ni], acc[mi + 4][ni]);
    __builtin_amdgcn_s_setprio(0);
    __builtin_amdgcn_sched_barrier(0);     // no ds_read may sink below barrier
    __syncthreads();                       // kt retired (vmcnt+lgkm drained)
    __builtin_amdgcn_sched_barrier(0);     // STAGE may not hoist above barrier
    if (kt < 6) STAGE_B(kt + 2, kt & 1)
    __builtin_amdgcn_sched_barrier(0);     // next reads may not hoist above
  }

  // ------------------ fold: per-row top-2 over this block's 256 cols ------
  uint2* mrg = (uint2*)smem;   // [256 rows][4 wn][2 slots] = 16KB

  float cnv[4];
#pragma unroll
  for (int ni = 0; ni < 4; ++ni) cnv[ni] = cn[c0 + wn * 64 + ni * 16 + lr];

#pragma unroll
  for (int mi = 0; mi < 8; ++mi) {
#pragma unroll
    for (int r = 0; r < 4; ++r) {
      float s1 = __builtin_inff(), s2 = __builtin_inff();
      int   i1 = KCODES, i2 = KCODES;
#pragma unroll
      for (int ni = 0; ni < 4; ++ni) {
        const float s = fmaf(-2.0f, acc[mi][ni][r], cnv[ni]);
        const int col = c0 + wn * 64 + ni * 16 + lr;
        const bool lt1 = s < s1;
        const bool lt2 = s < s2;
        s2 = lt1 ? s1 : (lt2 ? s   : s2);
        i2 = lt1 ? i1 : (lt2 ? col : i2);
        s1 = lt1 ? s   : s1;
        i1 = lt1 ? col : i1;
      }
#pragma unroll
      for (int off = 1; off < 16; off <<= 1) {
        const float t1 = __shfl_xor(s1, off, 64);
        const int   j1 = __shfl_xor(i1, off, 64);
        const float t2 = __shfl_xor(s2, off, 64);
        const int   j2 = __shfl_xor(i2, off, 64);
        const bool c1 = (t1 < s1) || (t1 == s1 && j1 < i1);
        const float w1s = c1 ? t1 : s1; const int w1i = c1 ? j1 : i1;
        const float l1s = c1 ? s1 : t1; const int l1i = c1 ? i1 : j1;
        const bool c2 = (t2 < s2) || (t2 == s2 && j2 < i2);
        const float m2s = c2 ? t2 : s2; const int m2i = c2 ? j2 : i2;
        const bool c3 = (m2s < l1s) || (m2s == l1s && m2i < l1i);
        s2 = c3 ? m2s : l1s; i2 = c3 ? m2i : l1i;
        s1 = w1s;            i1 = w1i;
      }
      if (lr == 0) {
        const int row = wm * 128 + mi * 16 + lg * 4 + r;
        uint2 e0; e0.x = __float_as_uint(s1); e0.y = (uint32_t)i1;
        uint2 e1; e1.x = __float_as_uint(s2); e1.y = (uint32_t)i2;
        mrg[(row * 4 + wn) * 2 + 0] = e0;
        mrg[(row * 4 + wn) * 2 + 1] = e1;
      }
    }
  }
  __syncthreads();

  if (tid < 256) {
    const int row = tid;
    float s1 = __builtin_inff(), s2 = __builtin_inff();
    int   i1 = KCODES, i2 = KCODES;
    const uint2* mp = mrg + row * 8;
#pragma unroll
    for (int t = 0; t < 8; ++t) {
      const float s = __uint_as_float(mp[t].x);
      const int   i = (int)mp[t].y;
      if (s < s1 || (s == s1 && i < i1)) { s2 = s1; i2 = i1; s1 = s; i1 = i; }
      else if (s < s2 || (s == s2 && i < i2)) { s2 = s; i2 = i; }
    }
    uint4 o;
    o.x = __float_as_uint(s1); o.y = (uint32_t)i1;
    o.z = __float_as_uint(s2); o.w = (uint32_t)i2;
    *((uint4*)(cand2 + ((size_t)(r0 + row) * 32 + nb) * 4)) = o;
  }
#undef STAGE_B
#undef LDB
#undef LDA
}

// ---------------------------------------------------------------------------
// K5: top-select + exact fp32 rescore. One wave per row; lane l holds 1 of 64
// (score,idx) pairs. Margin 32 (>=7 sigma of fp8 score-noise difference).
// Fast path when exactly one candidate in margin.
// ---------------------------------------------------------------------------
__global__ __launch_bounds__(256) void rescore_kernel(
    const float* __restrict__ x, const float* __restrict__ cb,
    const uint32_t* __restrict__ cand2, int* __restrict__ idx_ws,
    float* __restrict__ out) {
  const int row = blockIdx.x * 4 + (threadIdx.x >> 6);
  const int l = threadIdx.x & 63;
  if (row == 0 && l == 0) out[(size_t)MROWS * DDIM + MROWS] = 0.0f;

  const uint2 pr = ((const uint2*)(cand2 + (size_t)row * 128))[l];
  const float s = __uint_as_float(pr.x);
  const int   ci = (int)pr.y;

  float bs = s; int bi = ci;
#pragma unroll
  for (int off = 1; off < 64; off <<= 1) {
    const float os = __shfl_xor(bs, off, 64);
    const int   oi = __shfl_xor(bi, off, 64);
    if (os < bs || (os == bs && oi < bi)) { bs = os; bi = oi; }
  }
  const float thr = bs + 32.0f;
  unsigned long long m = __ballot(s <= thr);

  if (__popcll(m) == 1) {
    if (l == 0) {
      idx_ws[row] = bi;
      out[(size_t)MROWS * DDIM + row] = (float)bi;
    }
    return;
  }

  const float4* x4 = (const float4*)(x + (size_t)row * DDIM);
  float4 xv[4];
#pragma unroll
  for (int i = 0; i < 4; ++i) xv[i] = x4[i * 64 + l];

  float bestS = __builtin_inff(); int bestI = KCODES;
  while (m) {
    const int b = __builtin_ctzll(m);
    m &= m - 1;
    const int code = __shfl(ci, b, 64);
    const float4* c4 = (const float4*)(cb + (size_t)code * DDIM);
    float dot = 0.f, nn = 0.f;
#pragma unroll
    for (int i = 0; i < 4; ++i) {
      const float4 cv = c4[i * 64 + l];
      dot = fmaf(xv[i].x, cv.x, dot); dot = fmaf(xv[i].y, cv.y, dot);
      dot = fmaf(xv[i].z, cv.z, dot); dot = fmaf(xv[i].w, cv.w, dot);
      nn  = fmaf(cv.x, cv.x, nn);     nn  = fmaf(cv.y, cv.y, nn);
      nn  = fmaf(cv.z, cv.z, nn);     nn  = fmaf(cv.w, cv.w, nn);
    }
#pragma unroll
    for (int off = 32; off > 0; off >>= 1) {
      dot += __shfl_xor(dot, off, 64);
      nn  += __shfl_xor(nn,  off, 64);
    }
    const float sc = nn - 2.0f * dot;
    if (sc < bestS || (sc == bestS && code < bestI)) { bestS = sc; bestI = code; }
  }
  if (l == 0) {
    idx_ws[row] = bestI;
    out[(size_t)MROWS * DDIM + row] = (float)bestI;
  }
}

// ---------------------------------------------------------------------------
// K6/K7: bf16 GEMM C = A[M][K] * B[N][K]^T (+bias). EPI==1: relu->bf16.
// EPI==2: f32 store.
// ---------------------------------------------------------------------------
template <int EPI>
__global__ __launch_bounds__(256) void gemm_bt_kernel(
    const unsigned short* __restrict__ A, const unsigned short* __restrict__ B,
    const float* __restrict__ bias, void* __restrict__ outp,
    int Nsize, int Kred, int nblk) {
  __shared__ unsigned short As[128 * 32];
  __shared__ unsigned short Bs[128 * 32];
  const int tid = threadIdx.x;
  const int l = tid & 63, w = tid >> 6;
  const int lr = l & 15, lg = l >> 4;
  const int wm = w >> 1, wn = w & 1;
  const int mb = blockIdx.x / nblk, nb = blockIdx.x % nblk;
  const int r0 = mb * 128, c0 = nb * 128;
  const int prow = tid >> 2, pcol = (tid & 3) * 8;

  f32x4 acc[4][4];
#pragma unroll
  for (int mi = 0; mi < 4; ++mi)
#pragma unroll
    for (int ni = 0; ni < 4; ++ni) acc[mi][ni] = 0.0f;

  const size_t aoff0 = (size_t)(r0 + prow) * Kred + pcol;
  const size_t aoff1 = aoff0 + (size_t)64 * Kred;
  const size_t boff0 = (size_t)(c0 + prow) * Kred + pcol;
  const size_t boff1 = boff0 + (size_t)64 * Kred;

  const int nks = Kred >> 5;
  for (int ks = 0; ks < nks; ++ks) {
    const int k0 = ks * 32;
    gload_lds16(A + aoff0 + k0, &As[tid * 8]);
    gload_lds16(A + aoff1 + k0, &As[2048 + tid * 8]);
    gload_lds16(B + boff0 + k0, &Bs[tid * 8]);
    gload_lds16(B + boff1 + k0, &Bs[2048 + tid * 8]);
    __syncthreads();

    bf16x8 af[4], bfv[4];
#pragma unroll
    for (int mi = 0; mi < 4; ++mi)
      af[mi] = *reinterpret_cast<const bf16x8*>(
          &As[(wm * 64 + mi * 16 + lr) * 32 + lg * 8]);
#pragma unroll
    for (int ni = 0; ni < 4; ++ni)
      bfv[ni] = *reinterpret_cast<const bf16x8*>(
          &Bs[(wn * 64 + ni * 16 + lr) * 32 + lg * 8]);
#pragma unroll
    for (int mi = 0; mi < 4; ++mi)
#pragma unroll
      for (int ni = 0; ni < 4; ++ni)
        acc[mi][ni] = __builtin_amdgcn_mfma_f32_16x16x32_bf16(
            af[mi], bfv[ni], acc[mi][ni], 0, 0, 0);
    __syncthreads();
  }

#pragma unroll
  for (int ni = 0; ni < 4; ++ni) {
    const int col = c0 + wn * 64 + ni * 16 + lr;
    const float bv = bias[col];
#pragma unroll
    for (int mi = 0; mi < 4; ++mi) {
#pragma unroll
      for (int r = 0; r < 4; ++r) {
        const int row = r0 + wm * 64 + mi * 16 + lg * 4 + r;
        const float v = acc[mi][ni][r] + bv;
        if (EPI == 1) {
          ((unsigned short*)outp)[(size_t)row * Nsize + col] =
              f2bf(fmaxf(v, 0.0f));
        } else {
          ((float*)outp)[(size_t)row * Nsize + col] = v;
        }
      }
    }
  }
}

// ---------------------------------------------------------------------------
// K8: recon[row] = dec[idx[row]] gather-write + fused commitment loss.
// ---------------------------------------------------------------------------
__global__ __launch_bounds__(256) void epilogue_kernel(
    const float* __restrict__ x, const float* __restrict__ cb,
    const float* __restrict__ dec, const int* __restrict__ idx_ws,
    float* __restrict__ out) {
  __shared__ float wsum[4];
  const int r = blockIdx.x, t = threadIdx.x;
  const int code = idx_ws[r];
  const float4 dv = ((const float4*)(dec + (size_t)code * DDIM))[t];
  ((float4*)(out + (size_t)r * DDIM))[t] = dv;
  const float4 xv = ((const float4*)(x + (size_t)r * DDIM))[t];
  const float4 cv = ((const float4*)(cb + (size_t)code * DDIM))[t];
  const float ex = xv.x - cv.x, ey = xv.y - cv.y;
  const float ez = xv.z - cv.z, ew = xv.w - cv.w;
  float pr = ex * ex + ey * ey + ez * ez + ew * ew;
  pr = waveReduceSum(pr);
  if ((t & 63) == 0) wsum[t >> 6] = pr;
  __syncthreads();
  if (t == 0) {
    const float total = wsum[0] + wsum[1] + wsum[2] + wsum[3];
    atomicAdd(out + (size_t)MROWS * DDIM + MROWS, total * (0.25f / 16777216.0f));
  }
}

// ---------------------------------------------------------------------------
extern "C" void kernel_launch(void* const* d_in, const int* in_sizes, int n_in,
                              void* d_out, int out_size, void* d_ws,
                              size_t ws_size, hipStream_t stream) {
  const float* features = (const float*)d_in[0];  // [8,2048,1024]
  const float* codebook = (const float*)d_in[1];  // [8192,1024]
  const float* w1 = (const float*)d_in[2];        // [1024,512]
  const float* b1 = (const float*)d_in[3];        // [512]
  const float* w2 = (const float*)d_in[4];        // [512,1024]
  const float* b2 = (const float*)d_in[5];        // [1024]
  float* out = (float*)d_out;
  char* ws = (char*)d_ws;

  uint8_t*        xq8 = (uint8_t*)(ws + 0);                // 16,777,216
  uint8_t*        cq8 = (uint8_t*)(ws + 16777216);         //  8,388,608
  unsigned short* cbb = (unsigned short*)(ws + 25165824);  // 16,777,216
  float*          cn  = (float*)(ws + 41943040);           //     32,768
  unsigned short* w1t = (unsigned short*)(ws + 41975808);  //  1,048,576
  unsigned short* w2t = (unsigned short*)(ws + 43024384);  //  1,048,576
  unsigned short* hb  = (unsigned short*)(ws + 44072960);  //  8,388,608
  float*          dec = (float*)(ws + 52461568);           // 33,554,432
  int*            idxw = (int*)(ws + 86016000);            //     65,536
  // cand2 (8 MB) aliases dec: consumed by rescore BEFORE gemm<2> writes dec
  // (stream-ordered -> safe).
  uint32_t*       cand2 = (uint32_t*)(ws + 52461568);

  cvt_x_kernel<<<8192, 256, 0, stream>>>(features, xq8, MROWS * DDIM / 8);
  cvt_cb_cn_kernel<<<KCODES, 256, 0, stream>>>(codebook, cbb, cq8, cn);
  transpose_w_kernel<<<2048, 256, 0, stream>>>(w1, w1t, DDIM, HDIM);
  transpose_w_kernel<<<2048, 256, 0, stream>>>(w2, w2t, HDIM, DDIM);

  coarse_kernel<<<(MROWS / 256) * (KCODES / 256), 512, 0, stream>>>(
      xq8, cq8, cn, cand2);
  rescore_kernel<<<MROWS / 4, 256, 0, stream>>>(features, codebook, cand2,
                                                idxw, out);

  // decode the codebook (8192 rows), then recon = dec[idx]
  gemm_bt_kernel<1><<<64 * (HDIM / 128), 256, 0, stream>>>(
      cbb, w1t, b1, hb, HDIM, DDIM, HDIM / 128);
  gemm_bt_kernel<2><<<64 * (DDIM / 128), 256, 0, stream>>>(
      hb, w2t, b2, dec, DDIM, HDIM, DDIM / 128);

  epilogue_kernel<<<MROWS, 256, 0, stream>>>(features, codebook, dec, idxw, out);
}

// Round 9
// 663.199 us; speedup vs baseline: 1.2323x; 1.2323x over previous
//
#include <hip/hip_runtime.h>
#include <hip/hip_fp8.h>
#include <stdint.h>

// ---------------------------------------------------------------------------
// VQ-VAE quantizer. Coarse: MX-fp8 mfma_scale_f32_16x16x128, 256x256 tile,
// 8 waves, BK=128, LDS dbuf 2x64KB. R9: counted-vmcnt schedule (R4's proven
// discipline): s_waitcnt vmcnt(8) + raw s_barrier per KT -- prefetch stays in
// flight across barriers (R7's __syncthreads drained it every KT).
// Prep kernels fused into one launch. Rescore margin 32 (validated R8).
// Sizes: M=B*T=16384, D=1024, K=8192 codes, H=512.
// ---------------------------------------------------------------------------

#define MROWS  16384
#define DDIM   1024
#define KCODES 8192
#define HDIM   512

typedef __attribute__((ext_vector_type(4))) float  f32x4;
typedef __attribute__((ext_vector_type(8))) __bf16 bf16x8;
typedef __attribute__((ext_vector_type(4))) int    i32x4;
typedef __attribute__((ext_vector_type(8))) int    i32x8;

__device__ __forceinline__ unsigned short f2bf(float f) {
  uint32_t b = __float_as_uint(f);
  b += 0x7FFFu + ((b >> 16) & 1u);          // RNE
  return (unsigned short)(b >> 16);
}

__device__ __forceinline__ uint32_t f2fp8(float f) {
  return (uint32_t)__hip_fp8_e4m3(f).__x;   // OCP e4m3fn, saturating
}

__device__ __forceinline__ void gload_lds16(const void* g, void* l) {
  __builtin_amdgcn_global_load_lds(
      (__attribute__((address_space(1))) void*)(uintptr_t)g,
      (__attribute__((address_space(3))) void*)(uint32_t)(uintptr_t)l,
      16, 0, 0);
}

__device__ __forceinline__ f32x4 mfma_mx(i32x8 a, i32x8 b, f32x4 c) {
  // cbsz=0 (A=fp8 e4m3), blgp=0 (B=fp8); scales: every byte 127 -> 2^0
  return __builtin_amdgcn_mfma_scale_f32_16x16x128_f8f6f4(
      a, b, c, 0, 0, 0, 0x7F7F7F7F, 0, 0x7F7F7F7F);
}

__device__ __forceinline__ float waveReduceSum(float v) {
#pragma unroll
  for (int off = 32; off > 0; off >>= 1) v += __shfl_xor(v, off, 64);
  return v;
}

// ---------------------------------------------------------------------------
// K0: fused prep. blocks [0,8192): features f32->fp8 (2048 elems/block);
// [8192,16384): codebook row -> bf16 + fp8 + norm; [16384,18432): w1^T;
// [18432,20480): w2^T.
// ---------------------------------------------------------------------------
__global__ __launch_bounds__(256) void prep_kernel(
    const float* __restrict__ features, const float* __restrict__ codebook,
    const float* __restrict__ w1, const float* __restrict__ w2,
    uint8_t* __restrict__ xq8, uint8_t* __restrict__ cq8,
    unsigned short* __restrict__ cbb, float* __restrict__ cn,
    unsigned short* __restrict__ w1t, unsigned short* __restrict__ w2t) {
  __shared__ float wsum[4];
  const int bid = blockIdx.x, t = threadIdx.x;
  if (bid < 8192) {
    const int id = bid * 256 + t;
    const float4 v0 = ((const float4*)features)[id * 2];
    const float4 v1 = ((const float4*)features)[id * 2 + 1];
    uint2 u;
    u.x = f2fp8(v0.x) | (f2fp8(v0.y) << 8) | (f2fp8(v0.z) << 16) |
          (f2fp8(v0.w) << 24);
    u.y = f2fp8(v1.x) | (f2fp8(v1.y) << 8) | (f2fp8(v1.z) << 16) |
          (f2fp8(v1.w) << 24);
    ((uint2*)xq8)[id] = u;
  } else if (bid < 16384) {
    const int k = bid - 8192;
    const float4 v = ((const float4*)(codebook + (size_t)k * DDIM))[t];
    ushort4 u;
    u.x = f2bf(v.x); u.y = f2bf(v.y); u.z = f2bf(v.z); u.w = f2bf(v.w);
    ((ushort4*)(cbb + (size_t)k * DDIM))[t] = u;
    const uint32_t p8 = f2fp8(v.x) | (f2fp8(v.y) << 8) | (f2fp8(v.z) << 16) |
                        (f2fp8(v.w) << 24);
    ((uint32_t*)(cq8 + (size_t)k * DDIM))[t] = p8;
    float p = v.x * v.x + v.y * v.y + v.z * v.z + v.w * v.w;
    p = waveReduceSum(p);
    if ((t & 63) == 0) wsum[t >> 6] = p;
    __syncthreads();
    if (t == 0) cn[k] = wsum[0] + wsum[1] + wsum[2] + wsum[3];
  } else if (bid < 18432) {
    const int id = (bid - 16384) * 256 + t;       // w1 [1024][512] -> [512][1024]
    const int c = id / 1024, r = id % 1024;
    w1t[id] = f2bf(w1[(size_t)r * 512 + c]);
  } else {
    const int id = (bid - 18432) * 256 + t;       // w2 [512][1024] -> [1024][512]
    const int c = id / 512, r = id % 512;
    w2t[id] = f2bf(w2[(size_t)r * 1024 + c]);
  }
}

// ---------------------------------------------------------------------------
// K4: coarse scores = cn[k] - 2 * (xq . cq) via MX-fp8 MFMA (K=128).
// 256 rows x 256 codes per block, 8 waves (wm 0..1 x wn 0..3), 8 K-tiles.
// LDS dbuf 2x64KB, XOR swizzle byte^=((row&7)<<4), pre-swizzled global src.
// Schedule (R4-proven): prologue stages kt0+kt1 (16 loads/wave in flight);
// per KT: {vmcnt(8) -> own kt loads landed; s_barrier -> all waves' landed;
// ds_read+MFMA; s_barrier -> buf free; STAGE(kt+2)}. Counted vmcnt only
// (never 0 mid-loop); sched_barrier(0) pins around every STAGE + waits.
// Fold: per-row top-2 over 256 cols -> cand2[row][nb] (nb 0..31).
// ---------------------------------------------------------------------------
__global__ __launch_bounds__(512, 2) void coarse_kernel(
    const uint8_t* __restrict__ xq,   // [MROWS][DDIM] fp8
    const uint8_t* __restrict__ cq,   // [KCODES][DDIM] fp8
    const float* __restrict__ cn,     // [KCODES]
    uint32_t* __restrict__ cand2)     // [MROWS][32][4]
{
  __shared__ char smem[131072];   // 2 x (A 32KB + B 32KB); fold scratch aliased

  const int tid = threadIdx.x;
  const int l = tid & 63, w = tid >> 6;
  const int lr = l & 15, lg = l >> 4;
  const int wm = w >> 2, wn = w & 3;

  // bijective XCD swizzle (nwg = 2048 = 8 * 256)
  const int bid = blockIdx.x;
  const int swz = (bid & 7) * 256 + (bid >> 3);
  const int mb = swz >> 5, nb = swz & 31;
  const int r0 = mb * 256, c0 = nb * 256;

  // staging: linear LDS dest tid*16 (+j*8192); that chunk holds
  // global row = tid>>3 (+j*64), col byte = ((tid&7)*16) ^ ((row&7)<<4)
  const int srow = tid >> 3;                                   // 0..63
  const int scolb = ((tid & 7) * 16) ^ ((srow & 7) << 4);
  const uint8_t* aSrc = xq + (size_t)(r0 + srow) * DDIM + scolb;
  const uint8_t* bSrc = cq + (size_t)(c0 + srow) * DDIM + scolb;
  const int dBase = tid * 16;

  // fragment ds_read offsets. row&7 == lr&7 (row = multiple-of-16 + lr)
  const int sxor = (lr & 7) << 4;
  const int kLo = (lg * 32) ^ sxor;
  const int kHi = (lg * 32 + 16) ^ sxor;
  const int aRow = (wm * 128 + lr) * 128;           // + mi*2048
  const int bRow = 32768 + (wn * 64 + lr) * 128;    // + ni*2048

#define STAGE(KT, BUF)                                                        \
  {                                                                           \
    char* sb = smem + (BUF) * 65536;                                          \
    _Pragma("unroll")                                                         \
    for (int j = 0; j < 4; ++j)                                               \
      gload_lds16(aSrc + (size_t)j * 65536 + (KT) * 128,                      \
                  sb + dBase + j * 8192);                                     \
    _Pragma("unroll")                                                         \
    for (int j = 0; j < 4; ++j)                                               \
      gload_lds16(bSrc + (size_t)j * 65536 + (KT) * 128,                      \
                  sb + 32768 + dBase + j * 8192);                             \
  }

#define LDFRAG(dst, off)                                                      \
  {                                                                           \
    i32x4 _lo = *(const i32x4*)(ab + (off) + kLo);                            \
    i32x4 _hi = *(const i32x4*)(ab + (off) + kHi);                            \
    dst = __builtin_shufflevector(_lo, _hi, 0, 1, 2, 3, 4, 5, 6, 7);          \
  }

  f32x4 acc[8][4];
#pragma unroll
  for (int mi = 0; mi < 8; ++mi)
#pragma unroll
    for (int ni = 0; ni < 4; ++ni) acc[mi][ni] = 0.0f;

  // prologue: stage kt0 -> buf0, kt1 -> buf1 (16 loads/wave in flight)
  __builtin_amdgcn_sched_barrier(0);
  STAGE(0, 0)
  STAGE(1, 1)
  __builtin_amdgcn_sched_barrier(0);

#pragma unroll 1
  for (int kt = 0; kt < 8; ++kt) {
    const char* ab = smem + (kt & 1) * 65536;
    __builtin_amdgcn_sched_barrier(0);
    if (kt == 7) { asm volatile("s_waitcnt vmcnt(0)" ::: "memory"); }
    else         { asm volatile("s_waitcnt vmcnt(8)" ::: "memory"); }
    __builtin_amdgcn_s_barrier();          // all waves' kt loads landed
    __builtin_amdgcn_sched_barrier(0);

    i32x8 bf[4], af[4];
#pragma unroll
    for (int ni = 0; ni < 4; ++ni) LDFRAG(bf[ni], bRow + ni * 2048)
#pragma unroll
    for (int mi = 0; mi < 4; ++mi) LDFRAG(af[mi], aRow + mi * 2048)
    __builtin_amdgcn_s_setprio(1);
#pragma unroll
    for (int mi = 0; mi < 4; ++mi)
#pragma unroll
      for (int ni = 0; ni < 4; ++ni)
        acc[mi][ni] = mfma_mx(af[mi], bf[ni], acc[mi][ni]);
    __builtin_amdgcn_s_setprio(0);
#pragma unroll
    for (int mi = 0; mi < 4; ++mi) LDFRAG(af[mi], aRow + (mi + 4) * 2048)
    __builtin_amdgcn_s_setprio(1);
#pragma unroll
    for (int mi = 0; mi < 4; ++mi)
#pragma unroll
      for (int ni = 0; ni < 4; ++ni)
        acc[mi + 4][ni] = mfma_mx(af[mi], bf[ni], acc[mi + 4][ni]);
    __builtin_amdgcn_s_setprio(0);

    __builtin_amdgcn_sched_barrier(0);     // no ds_read may sink below barrier
    __builtin_amdgcn_s_barrier();          // all waves done reading this buf
    __builtin_amdgcn_sched_barrier(0);     // STAGE may not hoist above barrier
    if (kt < 6) STAGE(kt + 2, kt & 1)
    __builtin_amdgcn_sched_barrier(0);     // next reads may not hoist above
  }

  // ------------------ fold: per-row top-2 over this block's 256 cols ------
  uint2* mrg = (uint2*)smem;   // [256 rows][4 wn][2 slots] = 16KB

  float cnv[4];
#pragma unroll
  for (int ni = 0; ni < 4; ++ni) cnv[ni] = cn[c0 + wn * 64 + ni * 16 + lr];

#pragma unroll
  for (int mi = 0; mi < 8; ++mi) {
#pragma unroll
    for (int r = 0; r < 4; ++r) {
      float s1 = __builtin_inff(), s2 = __builtin_inff();
      int   i1 = KCODES, i2 = KCODES;
#pragma unroll
      for (int ni = 0; ni < 4; ++ni) {
        const float s = fmaf(-2.0f, acc[mi][ni][r], cnv[ni]);
        const int col = c0 + wn * 64 + ni * 16 + lr;
        const bool lt1 = s < s1;
        const bool lt2 = s < s2;
        s2 = lt1 ? s1 : (lt2 ? s   : s2);
        i2 = lt1 ? i1 : (lt2 ? col : i2);
        s1 = lt1 ? s   : s1;
        i1 = lt1 ? col : i1;
      }
#pragma unroll
      for (int off = 1; off < 16; off <<= 1) {
        const float t1 = __shfl_xor(s1, off, 64);
        const int   j1 = __shfl_xor(i1, off, 64);
        const float t2 = __shfl_xor(s2, off, 64);
        const int   j2 = __shfl_xor(i2, off, 64);
        const bool c1 = (t1 < s1) || (t1 == s1 && j1 < i1);
        const float w1s = c1 ? t1 : s1; const int w1i = c1 ? j1 : i1;
        const float l1s = c1 ? s1 : t1; const int l1i = c1 ? i1 : j1;
        const bool c2 = (t2 < s2) || (t2 == s2 && j2 < i2);
        const float m2s = c2 ? t2 : s2; const int m2i = c2 ? j2 : i2;
        const bool c3 = (m2s < l1s) || (m2s == l1s && m2i < l1i);
        s2 = c3 ? m2s : l1s; i2 = c3 ? m2i : l1i;
        s1 = w1s;            i1 = w1i;
      }
      if (lr == 0) {
        const int row = wm * 128 + mi * 16 + lg * 4 + r;
        uint2 e0; e0.x = __float_as_uint(s1); e0.y = (uint32_t)i1;
        uint2 e1; e1.x = __float_as_uint(s2); e1.y = (uint32_t)i2;
        mrg[(row * 4 + wn) * 2 + 0] = e0;
        mrg[(row * 4 + wn) * 2 + 1] = e1;
      }
    }
  }
  __syncthreads();

  if (tid < 256) {
    const int row = tid;
    float s1 = __builtin_inff(), s2 = __builtin_inff();
    int   i1 = KCODES, i2 = KCODES;
    const uint2* mp = mrg + row * 8;
#pragma unroll
    for (int t = 0; t < 8; ++t) {
      const float s = __uint_as_float(mp[t].x);
      const int   i = (int)mp[t].y;
      if (s < s1 || (s == s1 && i < i1)) { s2 = s1; i2 = i1; s1 = s; i1 = i; }
      else if (s < s2 || (s == s2 && i < i2)) { s2 = s; i2 = i; }
    }
    uint4 o;
    o.x = __float_as_uint(s1); o.y = (uint32_t)i1;
    o.z = __float_as_uint(s2); o.w = (uint32_t)i2;
    *((uint4*)(cand2 + ((size_t)(r0 + row) * 32 + nb) * 4)) = o;
  }
#undef STAGE
#undef LDFRAG
}

// ---------------------------------------------------------------------------
// K5: top-select + exact fp32 rescore. One wave per row; lane l holds 1 of 64
// (score,idx) pairs. Margin 32 (>=8 sigma of fp8 score-noise difference,
// validated R8). Fast path when exactly one candidate in margin.
// ---------------------------------------------------------------------------
__global__ __launch_bounds__(256) void rescore_kernel(
    const float* __restrict__ x, const float* __restrict__ cb,
    const uint32_t* __restrict__ cand2, int* __restrict__ idx_ws,
    float* __restrict__ out) {
  const int row = blockIdx.x * 4 + (threadIdx.x >> 6);
  const int l = threadIdx.x & 63;
  if (row == 0 && l == 0) out[(size_t)MROWS * DDIM + MROWS] = 0.0f;

  const uint2 pr = ((const uint2*)(cand2 + (size_t)row * 128))[l];
  const float s = __uint_as_float(pr.x);
  const int   ci = (int)pr.y;

  float bs = s; int bi = ci;
#pragma unroll
  for (int off = 1; off < 64; off <<= 1) {
    const float os = __shfl_xor(bs, off, 64);
    const int   oi = __shfl_xor(bi, off, 64);
    if (os < bs || (os == bs && oi < bi)) { bs = os; bi = oi; }
  }
  const float thr = bs + 32.0f;
  unsigned long long m = __ballot(s <= thr);

  if (__popcll(m) == 1) {
    if (l == 0) {
      idx_ws[row] = bi;
      out[(size_t)MROWS * DDIM + row] = (float)bi;
    }
    return;
  }

  const float4* x4 = (const float4*)(x + (size_t)row * DDIM);
  float4 xv[4];
#pragma unroll
  for (int i = 0; i < 4; ++i) xv[i] = x4[i * 64 + l];

  float bestS = __builtin_inff(); int bestI = KCODES;
  while (m) {
    const int b = __builtin_ctzll(m);
    m &= m - 1;
    const int code = __shfl(ci, b, 64);
    const float4* c4 = (const float4*)(cb + (size_t)code * DDIM);
    float dot = 0.f, nn = 0.f;
#pragma unroll
    for (int i = 0; i < 4; ++i) {
      const float4 cv = c4[i * 64 + l];
      dot = fmaf(xv[i].x, cv.x, dot); dot = fmaf(xv[i].y, cv.y, dot);
      dot = fmaf(xv[i].z, cv.z, dot); dot = fmaf(xv[i].w, cv.w, dot);
      nn  = fmaf(cv.x, cv.x, nn);     nn  = fmaf(cv.y, cv.y, nn);
      nn  = fmaf(cv.z, cv.z, nn);     nn  = fmaf(cv.w, cv.w, nn);
    }
#pragma unroll
    for (int off = 32; off > 0; off >>= 1) {
      dot += __shfl_xor(dot, off, 64);
      nn  += __shfl_xor(nn,  off, 64);
    }
    const float sc = nn - 2.0f * dot;
    if (sc < bestS || (sc == bestS && code < bestI)) { bestS = sc; bestI = code; }
  }
  if (l == 0) {
    idx_ws[row] = bestI;
    out[(size_t)MROWS * DDIM + row] = (float)bestI;
  }
}

// ---------------------------------------------------------------------------
// K6/K7: bf16 GEMM C = A[M][K] * B[N][K]^T (+bias). EPI==1: relu->bf16.
// EPI==2: f32 store.
// ---------------------------------------------------------------------------
template <int EPI>
__global__ __launch_bounds__(256) void gemm_bt_kernel(
    const unsigned short* __restrict__ A, const unsigned short* __restrict__ B,
    const float* __restrict__ bias, void* __restrict__ outp,
    int Nsize, int Kred, int nblk) {
  __shared__ unsigned short As[128 * 32];
  __shared__ unsigned short Bs[128 * 32];
  const int tid = threadIdx.x;
  const int l = tid & 63, w = tid >> 6;
  const int lr = l & 15, lg = l >> 4;
  const int wm = w >> 1, wn = w & 1;
  const int mb = blockIdx.x / nblk, nb = blockIdx.x % nblk;
  const int r0 = mb * 128, c0 = nb * 128;
  const int prow = tid >> 2, pcol = (tid & 3) * 8;

  f32x4 acc[4][4];
#pragma unroll
  for (int mi = 0; mi < 4; ++mi)
#pragma unroll
    for (int ni = 0; ni < 4; ++ni) acc[mi][ni] = 0.0f;

  const size_t aoff0 = (size_t)(r0 + prow) * Kred + pcol;
  const size_t aoff1 = aoff0 + (size_t)64 * Kred;
  const size_t boff0 = (size_t)(c0 + prow) * Kred + pcol;
  const size_t boff1 = boff0 + (size_t)64 * Kred;

  const int nks = Kred >> 5;
  for (int ks = 0; ks < nks; ++ks) {
    const int k0 = ks * 32;
    gload_lds16(A + aoff0 + k0, &As[tid * 8]);
    gload_lds16(A + aoff1 + k0, &As[2048 + tid * 8]);
    gload_lds16(B + boff0 + k0, &Bs[tid * 8]);
    gload_lds16(B + boff1 + k0, &Bs[2048 + tid * 8]);
    __syncthreads();

    bf16x8 af[4], bfv[4];
#pragma unroll
    for (int mi = 0; mi < 4; ++mi)
      af[mi] = *reinterpret_cast<const bf16x8*>(
          &As[(wm * 64 + mi * 16 + lr) * 32 + lg * 8]);
#pragma unroll
    for (int ni = 0; ni < 4; ++ni)
      bfv[ni] = *reinterpret_cast<const bf16x8*>(
          &Bs[(wn * 64 + ni * 16 + lr) * 32 + lg * 8]);
#pragma unroll
    for (int mi = 0; mi < 4; ++mi)
#pragma unroll
      for (int ni = 0; ni < 4; ++ni)
        acc[mi][ni] = __builtin_amdgcn_mfma_f32_16x16x32_bf16(
            af[mi], bfv[ni], acc[mi][ni], 0, 0, 0);
    __syncthreads();
  }

#pragma unroll
  for (int ni = 0; ni < 4; ++ni) {
    const int col = c0 + wn * 64 + ni * 16 + lr;
    const float bv = bias[col];
#pragma unroll
    for (int mi = 0; mi < 4; ++mi) {
#pragma unroll
      for (int r = 0; r < 4; ++r) {
        const int row = r0 + wm * 64 + mi * 16 + lg * 4 + r;
        const float v = acc[mi][ni][r] + bv;
        if (EPI == 1) {
          ((unsigned short*)outp)[(size_t)row * Nsize + col] =
              f2bf(fmaxf(v, 0.0f));
        } else {
          ((float*)outp)[(size_t)row * Nsize + col] = v;
        }
      }
    }
  }
}

// ---------------------------------------------------------------------------
// K8: recon[row] = dec[idx[row]] gather-write + fused commitment loss.
// ---------------------------------------------------------------------------
__global__ __launch_bounds__(256) void epilogue_kernel(
    const float* __restrict__ x, const float* __restrict__ cb,
    const float* __restrict__ dec, const int* __restrict__ idx_ws,
    float* __restrict__ out) {
  __shared__ float wsum[4];
  const int r = blockIdx.x, t = threadIdx.x;
  const int code = idx_ws[r];
  const float4 dv = ((const float4*)(dec + (size_t)code * DDIM))[t];
  ((float4*)(out + (size_t)r * DDIM))[t] = dv;
  const float4 xv = ((const float4*)(x + (size_t)r * DDIM))[t];
  const float4 cv = ((const float4*)(cb + (size_t)code * DDIM))[t];
  const float ex = xv.x - cv.x, ey = xv.y - cv.y;
  const float ez = xv.z - cv.z, ew = xv.w - cv.w;
  float pr = ex * ex + ey * ey + ez * ez + ew * ew;
  pr = waveReduceSum(pr);
  if ((t & 63) == 0) wsum[t >> 6] = pr;
  __syncthreads();
  if (t == 0) {
    const float total = wsum[0] + wsum[1] + wsum[2] + wsum[3];
    atomicAdd(out + (size_t)MROWS * DDIM + MROWS, total * (0.25f / 16777216.0f));
  }
}

// ---------------------------------------------------------------------------
extern "C" void kernel_launch(void* const* d_in, const int* in_sizes, int n_in,
                              void* d_out, int out_size, void* d_ws,
                              size_t ws_size, hipStream_t stream) {
  const float* features = (const float*)d_in[0];  // [8,2048,1024]
  const float* codebook = (const float*)d_in[1];  // [8192,1024]
  const float* w1 = (const float*)d_in[2];        // [1024,512]
  const float* b1 = (const float*)d_in[3];        // [512]
  const float* w2 = (const float*)d_in[4];        // [512,1024]
  const float* b2 = (const float*)d_in[5];        // [1024]
  float* out = (float*)d_out;
  char* ws = (char*)d_ws;

  uint8_t*        xq8 = (uint8_t*)(ws + 0);                // 16,777,216
  uint8_t*        cq8 = (uint8_t*)(ws + 16777216);         //  8,388,608
  unsigned short* cbb = (unsigned short*)(ws + 25165824);  // 16,777,216
  float*          cn  = (float*)(ws + 41943040);           //     32,768
  unsigned short* w1t = (unsigned short*)(ws + 41975808);  //  1,048,576
  unsigned short* w2t = (unsigned short*)(ws + 43024384);  //  1,048,576
  unsigned short* hb  = (unsigned short*)(ws + 44072960);  //  8,388,608
  float*          dec = (float*)(ws + 52461568);           // 33,554,432
  int*            idxw = (int*)(ws + 86016000);            //     65,536
  // cand2 (8 MB) aliases dec: consumed by rescore BEFORE gemm<2> writes dec
  // (stream-ordered -> safe).
  uint32_t*       cand2 = (uint32_t*)(ws + 52461568);

  prep_kernel<<<20480, 256, 0, stream>>>(features, codebook, w1, w2,
                                         xq8, cq8, cbb, cn, w1t, w2t);

  coarse_kernel<<<(MROWS / 256) * (KCODES / 256), 512, 0, stream>>>(
      xq8, cq8, cn, cand2);
  rescore_kernel<<<MROWS / 4, 256, 0, stream>>>(features, codebook, cand2,
                                                idxw, out);

  // decode the codebook (8192 rows), then recon = dec[idx]
  gemm_bt_kernel<1><<<64 * (HDIM / 128), 256, 0, stream>>>(
      cbb, w1t, b1, hb, HDIM, DDIM, HDIM / 128);
  gemm_bt_kernel<2><<<64 * (DDIM / 128), 256, 0, stream>>>(
      hb, w2t, b2, dec, DDIM, HDIM, DDIM / 128);

  epilogue_kernel<<<MROWS, 256, 0, stream>>>(features, codebook, dec, idxw, out);
}

// Round 10
// 599.011 us; speedup vs baseline: 1.3644x; 1.1072x over previous
//
#include <hip/hip_runtime.h>
#include <hip/hip_fp8.h>
#include <stdint.h>

// ---------------------------------------------------------------------------
// VQ-VAE quantizer. R10: coarse = m148-replica -- MX-fp8 K=128 MFMA on the
// m97 128x128 structure: 4 waves (2x2), acc[4][4] (64 AGPR), single-buffer
// LDS 32KB, simple stage->sync->compute->sync loop, 3 waves/SIMD via
// __launch_bounds__(256,3). Cross-block overlap (m114) hides the drain.
// Sizes: M=B*T=16384, D=1024, K=8192 codes, H=512.
// ---------------------------------------------------------------------------

#define MROWS  16384
#define DDIM   1024
#define KCODES 8192
#define HDIM   512

typedef __attribute__((ext_vector_type(4))) float  f32x4;
typedef __attribute__((ext_vector_type(8))) __bf16 bf16x8;
typedef __attribute__((ext_vector_type(4))) int    i32x4;
typedef __attribute__((ext_vector_type(8))) int    i32x8;

__device__ __forceinline__ unsigned short f2bf(float f) {
  uint32_t b = __float_as_uint(f);
  b += 0x7FFFu + ((b >> 16) & 1u);          // RNE
  return (unsigned short)(b >> 16);
}

__device__ __forceinline__ uint32_t f2fp8(float f) {
  return (uint32_t)__hip_fp8_e4m3(f).__x;   // OCP e4m3fn, saturating
}

__device__ __forceinline__ void gload_lds16(const void* g, void* l) {
  __builtin_amdgcn_global_load_lds(
      (__attribute__((address_space(1))) void*)(uintptr_t)g,
      (__attribute__((address_space(3))) void*)(uint32_t)(uintptr_t)l,
      16, 0, 0);
}

__device__ __forceinline__ f32x4 mfma_mx(i32x8 a, i32x8 b, f32x4 c) {
  // cbsz=0 (A=fp8 e4m3), blgp=0 (B=fp8); scales: every byte 127 -> 2^0
  return __builtin_amdgcn_mfma_scale_f32_16x16x128_f8f6f4(
      a, b, c, 0, 0, 0, 0x7F7F7F7F, 0, 0x7F7F7F7F);
}

__device__ __forceinline__ float waveReduceSum(float v) {
#pragma unroll
  for (int off = 32; off > 0; off >>= 1) v += __shfl_xor(v, off, 64);
  return v;
}

// ---------------------------------------------------------------------------
// K0: fused prep. blocks [0,8192): features f32->fp8 (2048 elems/block);
// [8192,16384): codebook row -> bf16 + fp8 + norm; [16384,18432): w1^T;
// [18432,20480): w2^T.
// ---------------------------------------------------------------------------
__global__ __launch_bounds__(256) void prep_kernel(
    const float* __restrict__ features, const float* __restrict__ codebook,
    const float* __restrict__ w1, const float* __restrict__ w2,
    uint8_t* __restrict__ xq8, uint8_t* __restrict__ cq8,
    unsigned short* __restrict__ cbb, float* __restrict__ cn,
    unsigned short* __restrict__ w1t, unsigned short* __restrict__ w2t) {
  __shared__ float wsum[4];
  const int bid = blockIdx.x, t = threadIdx.x;
  if (bid < 8192) {
    const int id = bid * 256 + t;
    const float4 v0 = ((const float4*)features)[id * 2];
    const float4 v1 = ((const float4*)features)[id * 2 + 1];
    uint2 u;
    u.x = f2fp8(v0.x) | (f2fp8(v0.y) << 8) | (f2fp8(v0.z) << 16) |
          (f2fp8(v0.w) << 24);
    u.y = f2fp8(v1.x) | (f2fp8(v1.y) << 8) | (f2fp8(v1.z) << 16) |
          (f2fp8(v1.w) << 24);
    ((uint2*)xq8)[id] = u;
  } else if (bid < 16384) {
    const int k = bid - 8192;
    const float4 v = ((const float4*)(codebook + (size_t)k * DDIM))[t];
    ushort4 u;
    u.x = f2bf(v.x); u.y = f2bf(v.y); u.z = f2bf(v.z); u.w = f2bf(v.w);
    ((ushort4*)(cbb + (size_t)k * DDIM))[t] = u;
    const uint32_t p8 = f2fp8(v.x) | (f2fp8(v.y) << 8) | (f2fp8(v.z) << 16) |
                        (f2fp8(v.w) << 24);
    ((uint32_t*)(cq8 + (size_t)k * DDIM))[t] = p8;
    float p = v.x * v.x + v.y * v.y + v.z * v.z + v.w * v.w;
    p = waveReduceSum(p);
    if ((t & 63) == 0) wsum[t >> 6] = p;
    __syncthreads();
    if (t == 0) cn[k] = wsum[0] + wsum[1] + wsum[2] + wsum[3];
  } else if (bid < 18432) {
    const int id = (bid - 16384) * 256 + t;       // w1 [1024][512] -> [512][1024]
    const int c = id / 1024, r = id % 1024;
    w1t[id] = f2bf(w1[(size_t)r * 512 + c]);
  } else {
    const int id = (bid - 18432) * 256 + t;       // w2 [512][1024] -> [1024][512]
    const int c = id / 512, r = id % 512;
    w2t[id] = f2bf(w2[(size_t)r * 1024 + c]);
  }
}

// ---------------------------------------------------------------------------
// K4: coarse scores = cn[k] - 2 * (xq . cq) via MX-fp8 MFMA (K=128).
// 128 rows x 128 codes per block, 4 waves (wm x wn, 2x2), 8 K-tiles.
// LDS single buffer: A[128][128B] 16KB + B[128][128B] 16KB, XOR swizzle
// byte ^= ((row&7)<<4), pre-swizzled global source (rule 21), pinned STAGE.
// m97 loop: STAGE(kt) -> __syncthreads (drain) -> ds_read+MFMA ->
// __syncthreads. 3 blocks/CU give cross-block overlap of the drain (m114).
// Fold: per-row top-2 over 128 cols -> cand2[row][nb] (nb 0..63).
// ---------------------------------------------------------------------------
__global__ __launch_bounds__(256, 3) void coarse_kernel(
    const uint8_t* __restrict__ xq,   // [MROWS][DDIM] fp8
    const uint8_t* __restrict__ cq,   // [KCODES][DDIM] fp8
    const float* __restrict__ cn,     // [KCODES]
    uint32_t* __restrict__ cand2)     // [MROWS][64][4]
{
  __shared__ char smem[32768];   // A 16KB + B 16KB; fold scratch aliased

  const int tid = threadIdx.x;
  const int l = tid & 63, w = tid >> 6;
  const int lr = l & 15, lg = l >> 4;
  const int wm = w >> 1, wn = w & 1;

  // bijective XCD swizzle (nwg = 8192 = 8 * 1024)
  const int bid = blockIdx.x;
  const int swz = (bid & 7) * 1024 + (bid >> 3);
  const int mb = swz >> 6, nb = swz & 63;
  const int r0 = mb * 128, c0 = nb * 128;

  // staging: linear LDS dest tid*16 (+j*4096); that chunk holds
  // global row = (tid>>3)+j*32, col byte = ((tid&7)*16) ^ ((row&7)<<4)
  const int scolb = ((tid & 7) * 16) ^ (((tid >> 3) & 7) << 4);
  const uint8_t* aSrc = xq + (size_t)(r0 + (tid >> 3)) * DDIM + scolb;
  const uint8_t* bSrc = cq + (size_t)(c0 + (tid >> 3)) * DDIM + scolb;
  const int dBase = tid * 16;

  // fragment ds_read offsets. row&7 == lr&7 (row = multiple-of-16 + lr)
  const int sxor = (lr & 7) << 4;
  const int kLo = (lg * 32) ^ sxor;
  const int kHi = (lg * 32 + 16) ^ sxor;
  const int aRow = (wm * 64 + lr) * 128;            // + mi*2048
  const int bRow = 16384 + (wn * 64 + lr) * 128;    // + ni*2048

#define STAGE(KT)                                                             \
  {                                                                           \
    _Pragma("unroll")                                                         \
    for (int j = 0; j < 4; ++j)                                               \
      gload_lds16(aSrc + (size_t)j * 32 * DDIM + (KT) * 128,                  \
                  smem + dBase + j * 4096);                                   \
    _Pragma("unroll")                                                         \
    for (int j = 0; j < 4; ++j)                                               \
      gload_lds16(bSrc + (size_t)j * 32 * DDIM + (KT) * 128,                  \
                  smem + 16384 + dBase + j * 4096);                           \
  }

#define LDFRAG(dst, off)                                                      \
  {                                                                           \
    i32x4 _lo = *(const i32x4*)(smem + (off) + kLo);                          \
    i32x4 _hi = *(const i32x4*)(smem + (off) + kHi);                          \
    dst = __builtin_shufflevector(_lo, _hi, 0, 1, 2, 3, 4, 5, 6, 7);          \
  }

  f32x4 acc[4][4];
#pragma unroll
  for (int mi = 0; mi < 4; ++mi)
#pragma unroll
    for (int ni = 0; ni < 4; ++ni) acc[mi][ni] = 0.0f;

#pragma unroll 1
  for (int kt = 0; kt < 8; ++kt) {
    __builtin_amdgcn_sched_barrier(0);
    STAGE(kt)
    __builtin_amdgcn_sched_barrier(0);
    __syncthreads();                        // loads landed (vmcnt drained)

    i32x8 bf[4];
#pragma unroll
    for (int ni = 0; ni < 4; ++ni) LDFRAG(bf[ni], bRow + ni * 2048)
#pragma unroll
    for (int mi = 0; mi < 4; ++mi) {
      i32x8 af;
      LDFRAG(af, aRow + mi * 2048)
      __builtin_amdgcn_s_setprio(1);
#pragma unroll
      for (int ni = 0; ni < 4; ++ni)
        acc[mi][ni] = mfma_mx(af, bf[ni], acc[mi][ni]);
      __builtin_amdgcn_s_setprio(0);
    }

    __builtin_amdgcn_sched_barrier(0);      // no ds_read may sink below
    __syncthreads();                        // all reads done; buffer free
  }

  // ------------------ fold: per-row top-2 over this block's 128 cols ------
  uint2* mrg = (uint2*)smem;   // [128 rows][2 wn][2 slots] = 4KB

  float cnv[4];
#pragma unroll
  for (int ni = 0; ni < 4; ++ni) cnv[ni] = cn[c0 + wn * 64 + ni * 16 + lr];

#pragma unroll
  for (int mi = 0; mi < 4; ++mi) {
#pragma unroll
    for (int r = 0; r < 4; ++r) {
      float s1 = __builtin_inff(), s2 = __builtin_inff();
      int   i1 = KCODES, i2 = KCODES;
#pragma unroll
      for (int ni = 0; ni < 4; ++ni) {
        const float s = fmaf(-2.0f, acc[mi][ni][r], cnv[ni]);
        const int col = c0 + wn * 64 + ni * 16 + lr;
        const bool lt1 = s < s1;
        const bool lt2 = s < s2;
        s2 = lt1 ? s1 : (lt2 ? s   : s2);
        i2 = lt1 ? i1 : (lt2 ? col : i2);
        s1 = lt1 ? s   : s1;
        i1 = lt1 ? col : i1;
      }
#pragma unroll
      for (int off = 1; off < 16; off <<= 1) {
        const float t1 = __shfl_xor(s1, off, 64);
        const int   j1 = __shfl_xor(i1, off, 64);
        const float t2 = __shfl_xor(s2, off, 64);
        const int   j2 = __shfl_xor(i2, off, 64);
        const bool c1 = (t1 < s1) || (t1 == s1 && j1 < i1);
        const float w1s = c1 ? t1 : s1; const int w1i = c1 ? j1 : i1;
        const float l1s = c1 ? s1 : t1; const int l1i = c1 ? i1 : j1;
        const bool c2 = (t2 < s2) || (t2 == s2 && j2 < i2);
        const float m2s = c2 ? t2 : s2; const int m2i = c2 ? j2 : i2;
        const bool c3 = (m2s < l1s) || (m2s == l1s && m2i < l1i);
        s2 = c3 ? m2s : l1s; i2 = c3 ? m2i : l1i;
        s1 = w1s;            i1 = w1i;
      }
      if (lr == 0) {
        const int row = wm * 64 + mi * 16 + lg * 4 + r;
        uint2 e0; e0.x = __float_as_uint(s1); e0.y = (uint32_t)i1;
        uint2 e1; e1.x = __float_as_uint(s2); e1.y = (uint32_t)i2;
        mrg[(row * 2 + wn) * 2 + 0] = e0;
        mrg[(row * 2 + wn) * 2 + 1] = e1;
      }
    }
  }
  __syncthreads();

  if (tid < 128) {
    const int row = tid;
    float s1 = __builtin_inff(), s2 = __builtin_inff();
    int   i1 = KCODES, i2 = KCODES;
    const uint2* mp = mrg + row * 4;
#pragma unroll
    for (int t = 0; t < 4; ++t) {
      const float s = __uint_as_float(mp[t].x);
      const int   i = (int)mp[t].y;
      if (s < s1 || (s == s1 && i < i1)) { s2 = s1; i2 = i1; s1 = s; i1 = i; }
      else if (s < s2 || (s == s2 && i < i2)) { s2 = s; i2 = i; }
    }
    uint4 o;
    o.x = __float_as_uint(s1); o.y = (uint32_t)i1;
    o.z = __float_as_uint(s2); o.w = (uint32_t)i2;
    *((uint4*)(cand2 + ((size_t)(r0 + row) * 64 + nb) * 4)) = o;
  }
#undef STAGE
#undef LDFRAG
}

// ---------------------------------------------------------------------------
// K5: top-select + exact fp32 rescore. One wave per row; lane l holds 2 of
// 128 (score,idx) pairs. Margin 32 (validated R8). Fast path when exactly
// one candidate in margin.
// ---------------------------------------------------------------------------
__global__ __launch_bounds__(256) void rescore_kernel(
    const float* __restrict__ x, const float* __restrict__ cb,
    const uint32_t* __restrict__ cand2, int* __restrict__ idx_ws,
    float* __restrict__ out) {
  const int row = blockIdx.x * 4 + (threadIdx.x >> 6);
  const int l = threadIdx.x & 63;
  if (row == 0 && l == 0) out[(size_t)MROWS * DDIM + MROWS] = 0.0f;

  const uint4 v = ((const uint4*)(cand2 + (size_t)row * 256))[l];
  const float sA = __uint_as_float(v.x); const int iA = (int)v.y;
  const float sB = __uint_as_float(v.z); const int iB = (int)v.w;

  // 64-lane (score, idx) min-reduce over both halves
  float bs; int bi;
  if (sA < sB || (sA == sB && iA < iB)) { bs = sA; bi = iA; }
  else                                  { bs = sB; bi = iB; }
#pragma unroll
  for (int off = 1; off < 64; off <<= 1) {
    const float os = __shfl_xor(bs, off, 64);
    const int   oi = __shfl_xor(bi, off, 64);
    if (os < bs || (os == bs && oi < bi)) { bs = os; bi = oi; }
  }
  const float thr = bs + 32.0f;
  unsigned long long mA = __ballot(sA <= thr);
  unsigned long long mB = __ballot(sB <= thr);

  if (__popcll(mA) + __popcll(mB) == 1) {
    if (l == 0) {
      idx_ws[row] = bi;
      out[(size_t)MROWS * DDIM + row] = (float)bi;
    }
    return;
  }

  const float4* x4 = (const float4*)(x + (size_t)row * DDIM);
  float4 xv[4];
#pragma unroll
  for (int i = 0; i < 4; ++i) xv[i] = x4[i * 64 + l];

  float bestS = __builtin_inff(); int bestI = KCODES;
#pragma unroll 1
  for (int half = 0; half < 2; ++half) {
    unsigned long long m = half ? mB : mA;
    const int myi = half ? iB : iA;
    while (m) {
      const int b = __builtin_ctzll(m);
      m &= m - 1;
      const int code = __shfl(myi, b, 64);
      const float4* c4 = (const float4*)(cb + (size_t)code * DDIM);
      float dot = 0.f, nn = 0.f;
#pragma unroll
      for (int i = 0; i < 4; ++i) {
        const float4 cv = c4[i * 64 + l];
        dot = fmaf(xv[i].x, cv.x, dot); dot = fmaf(xv[i].y, cv.y, dot);
        dot = fmaf(xv[i].z, cv.z, dot); dot = fmaf(xv[i].w, cv.w, dot);
        nn  = fmaf(cv.x, cv.x, nn);     nn  = fmaf(cv.y, cv.y, nn);
        nn  = fmaf(cv.z, cv.z, nn);     nn  = fmaf(cv.w, cv.w, nn);
      }
#pragma unroll
      for (int off = 32; off > 0; off >>= 1) {
        dot += __shfl_xor(dot, off, 64);
        nn  += __shfl_xor(nn,  off, 64);
      }
      const float sc = nn - 2.0f * dot;
      if (sc < bestS || (sc == bestS && code < bestI)) { bestS = sc; bestI = code; }
    }
  }
  if (l == 0) {
    idx_ws[row] = bestI;
    out[(size_t)MROWS * DDIM + row] = (float)bestI;
  }
}

// ---------------------------------------------------------------------------
// K6/K7: bf16 GEMM C = A[M][K] * B[N][K]^T (+bias). EPI==1: relu->bf16.
// EPI==2: f32 store.
// ---------------------------------------------------------------------------
template <int EPI>
__global__ __launch_bounds__(256) void gemm_bt_kernel(
    const unsigned short* __restrict__ A, const unsigned short* __restrict__ B,
    const float* __restrict__ bias, void* __restrict__ outp,
    int Nsize, int Kred, int nblk) {
  __shared__ unsigned short As[128 * 32];
  __shared__ unsigned short Bs[128 * 32];
  const int tid = threadIdx.x;
  const int l = tid & 63, w = tid >> 6;
  const int lr = l & 15, lg = l >> 4;
  const int wm = w >> 1, wn = w & 1;
  const int mb = blockIdx.x / nblk, nb = blockIdx.x % nblk;
  const int r0 = mb * 128, c0 = nb * 128;
  const int prow = tid >> 2, pcol = (tid & 3) * 8;

  f32x4 acc[4][4];
#pragma unroll
  for (int mi = 0; mi < 4; ++mi)
#pragma unroll
    for (int ni = 0; ni < 4; ++ni) acc[mi][ni] = 0.0f;

  const size_t aoff0 = (size_t)(r0 + prow) * Kred + pcol;
  const size_t aoff1 = aoff0 + (size_t)64 * Kred;
  const size_t boff0 = (size_t)(c0 + prow) * Kred + pcol;
  const size_t boff1 = boff0 + (size_t)64 * Kred;

  const int nks = Kred >> 5;
  for (int ks = 0; ks < nks; ++ks) {
    const int k0 = ks * 32;
    gload_lds16(A + aoff0 + k0, &As[tid * 8]);
    gload_lds16(A + aoff1 + k0, &As[2048 + tid * 8]);
    gload_lds16(B + boff0 + k0, &Bs[tid * 8]);
    gload_lds16(B + boff1 + k0, &Bs[2048 + tid * 8]);
    __syncthreads();

    bf16x8 af[4], bfv[4];
#pragma unroll
    for (int mi = 0; mi < 4; ++mi)
      af[mi] = *reinterpret_cast<const bf16x8*>(
          &As[(wm * 64 + mi * 16 + lr) * 32 + lg * 8]);
#pragma unroll
    for (int ni = 0; ni < 4; ++ni)
      bfv[ni] = *reinterpret_cast<const bf16x8*>(
          &Bs[(wn * 64 + ni * 16 + lr) * 32 + lg * 8]);
#pragma unroll
    for (int mi = 0; mi < 4; ++mi)
#pragma unroll
      for (int ni = 0; ni < 4; ++ni)
        acc[mi][ni] = __builtin_amdgcn_mfma_f32_16x16x32_bf16(
            af[mi], bfv[ni], acc[mi][ni], 0, 0, 0);
    __syncthreads();
  }

#pragma unroll
  for (int ni = 0; ni < 4; ++ni) {
    const int col = c0 + wn * 64 + ni * 16 + lr;
    const float bv = bias[col];
#pragma unroll
    for (int mi = 0; mi < 4; ++mi) {
#pragma unroll
      for (int r = 0; r < 4; ++r) {
        const int row = r0 + wm * 64 + mi * 16 + lg * 4 + r;
        const float v = acc[mi][ni][r] + bv;
        if (EPI == 1) {
          ((unsigned short*)outp)[(size_t)row * Nsize + col] =
              f2bf(fmaxf(v, 0.0f));
        } else {
          ((float*)outp)[(size_t)row * Nsize + col] = v;
        }
      }
    }
  }
}

// ---------------------------------------------------------------------------
// K8: recon[row] = dec[idx[row]] gather-write + fused commitment loss.
// ---------------------------------------------------------------------------
__global__ __launch_bounds__(256) void epilogue_kernel(
    const float* __restrict__ x, const float* __restrict__ cb,
    const float* __restrict__ dec, const int* __restrict__ idx_ws,
    float* __restrict__ out) {
  __shared__ float wsum[4];
  const int r = blockIdx.x, t = threadIdx.x;
  const int code = idx_ws[r];
  const float4 dv = ((const float4*)(dec + (size_t)code * DDIM))[t];
  ((float4*)(out + (size_t)r * DDIM))[t] = dv;
  const float4 xv = ((const float4*)(x + (size_t)r * DDIM))[t];
  const float4 cv = ((const float4*)(cb + (size_t)code * DDIM))[t];
  const float ex = xv.x - cv.x, ey = xv.y - cv.y;
  const float ez = xv.z - cv.z, ew = xv.w - cv.w;
  float pr = ex * ex + ey * ey + ez * ez + ew * ew;
  pr = waveReduceSum(pr);
  if ((t & 63) == 0) wsum[t >> 6] = pr;
  __syncthreads();
  if (t == 0) {
    const float total = wsum[0] + wsum[1] + wsum[2] + wsum[3];
    atomicAdd(out + (size_t)MROWS * DDIM + MROWS, total * (0.25f / 16777216.0f));
  }
}

// ---------------------------------------------------------------------------
extern "C" void kernel_launch(void* const* d_in, const int* in_sizes, int n_in,
                              void* d_out, int out_size, void* d_ws,
                              size_t ws_size, hipStream_t stream) {
  const float* features = (const float*)d_in[0];  // [8,2048,1024]
  const float* codebook = (const float*)d_in[1];  // [8192,1024]
  const float* w1 = (const float*)d_in[2];        // [1024,512]
  const float* b1 = (const float*)d_in[3];        // [512]
  const float* w2 = (const float*)d_in[4];        // [512,1024]
  const float* b2 = (const float*)d_in[5];        // [1024]
  float* out = (float*)d_out;
  char* ws = (char*)d_ws;

  uint8_t*        xq8 = (uint8_t*)(ws + 0);                // 16,777,216
  uint8_t*        cq8 = (uint8_t*)(ws + 16777216);         //  8,388,608
  unsigned short* cbb = (unsigned short*)(ws + 25165824);  // 16,777,216
  float*          cn  = (float*)(ws + 41943040);           //     32,768
  unsigned short* w1t = (unsigned short*)(ws + 41975808);  //  1,048,576
  unsigned short* w2t = (unsigned short*)(ws + 43024384);  //  1,048,576
  unsigned short* hb  = (unsigned short*)(ws + 44072960);  //  8,388,608
  float*          dec = (float*)(ws + 52461568);           // 33,554,432
  int*            idxw = (int*)(ws + 86016000);            //     65,536
  // cand2 (16 MB) aliases dec: consumed by rescore BEFORE gemm<2> writes dec
  // (stream-ordered -> safe).
  uint32_t*       cand2 = (uint32_t*)(ws + 52461568);

  prep_kernel<<<20480, 256, 0, stream>>>(features, codebook, w1, w2,
                                         xq8, cq8, cbb, cn, w1t, w2t);

  coarse_kernel<<<(MROWS / 128) * (KCODES / 128), 256, 0, stream>>>(
      xq8, cq8, cn, cand2);
  rescore_kernel<<<MROWS / 4, 256, 0, stream>>>(features, codebook, cand2,
                                                idxw, out);

  // decode the codebook (8192 rows), then recon = dec[idx]
  gemm_bt_kernel<1><<<64 * (HDIM / 128), 256, 0, stream>>>(
      cbb, w1t, b1, hb, HDIM, DDIM, HDIM / 128);
  gemm_bt_kernel<2><<<64 * (DDIM / 128), 256, 0, stream>>>(
      hb, w2t, b2, dec, DDIM, HDIM, DDIM / 128);

  epilogue_kernel<<<MROWS, 256, 0, stream>>>(features, codebook, dec, idxw, out);
}

// Round 11
// 494.760 us; speedup vs baseline: 1.6519x; 1.2107x over previous
//
#include <hip/hip_runtime.h>
#include <hip/hip_fp8.h>
#include <stdint.h>

// ---------------------------------------------------------------------------
// VQ-VAE quantizer. R11: coarse = R10's m148-replica main loop (validated)
// with the fold epilogue rebuilt: packed sortable keys (score_hi19|idx13) +
// LDS-transpose 2-phase reduction (16 ds_write_b64 + 8 uint4 reads per
// thread) replacing 256 shuffles/thread. Prep transposes now LDS-tiled.
// Sizes: M=B*T=16384, D=1024, K=8192 codes, H=512.
// ---------------------------------------------------------------------------

#define MROWS  16384
#define DDIM   1024
#define KCODES 8192
#define HDIM   512

typedef __attribute__((ext_vector_type(4))) float  f32x4;
typedef __attribute__((ext_vector_type(8))) __bf16 bf16x8;
typedef __attribute__((ext_vector_type(4))) int    i32x4;
typedef __attribute__((ext_vector_type(8))) int    i32x8;

__device__ __forceinline__ unsigned short f2bf(float f) {
  uint32_t b = __float_as_uint(f);
  b += 0x7FFFu + ((b >> 16) & 1u);          // RNE
  return (unsigned short)(b >> 16);
}

__device__ __forceinline__ uint32_t f2fp8(float f) {
  return (uint32_t)__hip_fp8_e4m3(f).__x;   // OCP e4m3fn, saturating
}

// sortable key: monotonic-f32 top 19 bits | idx (13 bits). Compare = score
// order with idx tie-break. Quantization error <= ~2 on scores ~1e3.
__device__ __forceinline__ uint32_t packkey(float s, int idx) {
  uint32_t u = __float_as_uint(s);
  u = ((int)u < 0) ? ~u : (u | 0x80000000u);
  return (u & 0xFFFFE000u) | (uint32_t)idx;
}
__device__ __forceinline__ float unpackkey(uint32_t k) {
  uint32_t u = k & 0xFFFFE000u;
  u = (u & 0x80000000u) ? (u ^ 0x80000000u) : ~u;
  return __uint_as_float(u);   // floor: result <= true score
}

__device__ __forceinline__ void gload_lds16(const void* g, void* l) {
  __builtin_amdgcn_global_load_lds(
      (__attribute__((address_space(1))) void*)(uintptr_t)g,
      (__attribute__((address_space(3))) void*)(uint32_t)(uintptr_t)l,
      16, 0, 0);
}

__device__ __forceinline__ f32x4 mfma_mx(i32x8 a, i32x8 b, f32x4 c) {
  return __builtin_amdgcn_mfma_scale_f32_16x16x128_f8f6f4(
      a, b, c, 0, 0, 0, 0x7F7F7F7F, 0, 0x7F7F7F7F);
}

__device__ __forceinline__ float waveReduceSum(float v) {
#pragma unroll
  for (int off = 32; off > 0; off >>= 1) v += __shfl_xor(v, off, 64);
  return v;
}

// ---------------------------------------------------------------------------
// K0: fused prep. [0,8192): features f32->fp8; [8192,16384): codebook ->
// bf16 + fp8 + norm; [16384,16896): w1^T 32x32 LDS tiles; [16896,17408): w2^T.
// ---------------------------------------------------------------------------
__global__ __launch_bounds__(256) void prep_kernel(
    const float* __restrict__ features, const float* __restrict__ codebook,
    const float* __restrict__ w1, const float* __restrict__ w2,
    uint8_t* __restrict__ xq8, uint8_t* __restrict__ cq8,
    unsigned short* __restrict__ cbb, float* __restrict__ cn,
    unsigned short* __restrict__ w1t, unsigned short* __restrict__ w2t) {
  __shared__ float wsum[4];
  __shared__ float tile[32][33];
  const int bid = blockIdx.x, t = threadIdx.x;
  if (bid < 8192) {
    const int id = bid * 256 + t;
    const float4 v0 = ((const float4*)features)[id * 2];
    const float4 v1 = ((const float4*)features)[id * 2 + 1];
    uint2 u;
    u.x = f2fp8(v0.x) | (f2fp8(v0.y) << 8) | (f2fp8(v0.z) << 16) |
          (f2fp8(v0.w) << 24);
    u.y = f2fp8(v1.x) | (f2fp8(v1.y) << 8) | (f2fp8(v1.z) << 16) |
          (f2fp8(v1.w) << 24);
    ((uint2*)xq8)[id] = u;
  } else if (bid < 16384) {
    const int k = bid - 8192;
    const float4 v = ((const float4*)(codebook + (size_t)k * DDIM))[t];
    ushort4 u;
    u.x = f2bf(v.x); u.y = f2bf(v.y); u.z = f2bf(v.z); u.w = f2bf(v.w);
    ((ushort4*)(cbb + (size_t)k * DDIM))[t] = u;
    const uint32_t p8 = f2fp8(v.x) | (f2fp8(v.y) << 8) | (f2fp8(v.z) << 16) |
                        (f2fp8(v.w) << 24);
    ((uint32_t*)(cq8 + (size_t)k * DDIM))[t] = p8;
    float p = v.x * v.x + v.y * v.y + v.z * v.z + v.w * v.w;
    p = waveReduceSum(p);
    if ((t & 63) == 0) wsum[t >> 6] = p;
    __syncthreads();
    if (t == 0) cn[k] = wsum[0] + wsum[1] + wsum[2] + wsum[3];
  } else {
    // LDS-tiled transpose f32[R][C] -> bf16[C][R], 32x32 tiles
    const float* src;
    unsigned short* dst;
    int R, C, t32;
    if (bid < 16896) { src = w1; dst = w1t; R = 1024; C = 512;
                       t32 = bid - 16384; }
    else             { src = w2; dst = w2t; R = 512;  C = 1024;
                       t32 = bid - 16896; }
    const int nct = C / 32;
    const int tr0 = (t32 / nct) * 32, tc0 = (t32 % nct) * 32;
    const int rr = t >> 3, cc = (t & 7) * 4;
    const float4 v = *(const float4*)(src + (size_t)(tr0 + rr) * C + tc0 + cc);
    tile[rr][cc + 0] = v.x; tile[rr][cc + 1] = v.y;
    tile[rr][cc + 2] = v.z; tile[rr][cc + 3] = v.w;
    __syncthreads();
    ushort4 o;
    o.x = f2bf(tile[cc + 0][rr]); o.y = f2bf(tile[cc + 1][rr]);
    o.z = f2bf(tile[cc + 2][rr]); o.w = f2bf(tile[cc + 3][rr]);
    *(ushort4*)(dst + (size_t)(tc0 + rr) * R + tr0 + cc) = o;
  }
}

// ---------------------------------------------------------------------------
// K4: coarse scores = cn[k] - 2 * (xq . cq) via MX-fp8 MFMA (K=128).
// 128x128 tile, 4 waves (2x2), 8 K-tiles, single-buffer LDS 32KB (validated
// R10 main loop). Fold: packed keys -> LDS transpose 2-phase ->
// cand2[row][nb] = top-2 keys (uint2), nb 0..63.
// ---------------------------------------------------------------------------
__global__ __launch_bounds__(256, 3) void coarse_kernel(
    const uint8_t* __restrict__ xq,   // [MROWS][DDIM] fp8
    const uint8_t* __restrict__ cq,   // [KCODES][DDIM] fp8
    const float* __restrict__ cn,     // [KCODES]
    uint32_t* __restrict__ cand2)     // [MROWS][64][2] keys
{
  __shared__ char smem[34816];   // main: 32KB (A16+B16); fold: 128x34 uint2

  const int tid = threadIdx.x;
  const int l = tid & 63, w = tid >> 6;
  const int lr = l & 15, lg = l >> 4;
  const int wm = w >> 1, wn = w & 1;

  // bijective XCD swizzle (nwg = 8192 = 8 * 1024)
  const int bid = blockIdx.x;
  const int swz = (bid & 7) * 1024 + (bid >> 3);
  const int mb = swz >> 6, nb = swz & 63;
  const int r0 = mb * 128, c0 = nb * 128;

  // staging: linear LDS dest tid*16 (+j*4096); chunk holds global
  // row = (tid>>3)+j*32, col byte = ((tid&7)*16) ^ ((row&7)<<4)
  const int scolb = ((tid & 7) * 16) ^ (((tid >> 3) & 7) << 4);
  const uint8_t* aSrc = xq + (size_t)(r0 + (tid >> 3)) * DDIM + scolb;
  const uint8_t* bSrc = cq + (size_t)(c0 + (tid >> 3)) * DDIM + scolb;
  const int dBase = tid * 16;

  // fragment ds_read offsets. row&7 == lr&7
  const int sxor = (lr & 7) << 4;
  const int kLo = (lg * 32) ^ sxor;
  const int kHi = (lg * 32 + 16) ^ sxor;
  const int aRow = (wm * 64 + lr) * 128;            // + mi*2048
  const int bRow = 16384 + (wn * 64 + lr) * 128;    // + ni*2048

#define STAGE(KT)                                                             \
  {                                                                           \
    _Pragma("unroll")                                                         \
    for (int j = 0; j < 4; ++j)                                               \
      gload_lds16(aSrc + (size_t)j * 32 * DDIM + (KT) * 128,                  \
                  smem + dBase + j * 4096);                                   \
    _Pragma("unroll")                                                         \
    for (int j = 0; j < 4; ++j)                                               \
      gload_lds16(bSrc + (size_t)j * 32 * DDIM + (KT) * 128,                  \
                  smem + 16384 + dBase + j * 4096);                           \
  }

#define LDFRAG(dst, off)                                                      \
  {                                                                           \
    i32x4 _lo = *(const i32x4*)(smem + (off) + kLo);                          \
    i32x4 _hi = *(const i32x4*)(smem + (off) + kHi);                          \
    dst = __builtin_shufflevector(_lo, _hi, 0, 1, 2, 3, 4, 5, 6, 7);          \
  }

  f32x4 acc[4][4];
#pragma unroll
  for (int mi = 0; mi < 4; ++mi)
#pragma unroll
    for (int ni = 0; ni < 4; ++ni) acc[mi][ni] = 0.0f;

#pragma unroll 1
  for (int kt = 0; kt < 8; ++kt) {
    __builtin_amdgcn_sched_barrier(0);
    STAGE(kt)
    __builtin_amdgcn_sched_barrier(0);
    __syncthreads();                        // loads landed (vmcnt drained)

    i32x8 bf[4];
#pragma unroll
    for (int ni = 0; ni < 4; ++ni) LDFRAG(bf[ni], bRow + ni * 2048)
#pragma unroll
    for (int mi = 0; mi < 4; ++mi) {
      i32x8 af;
      LDFRAG(af, aRow + mi * 2048)
      __builtin_amdgcn_s_setprio(1);
#pragma unroll
      for (int ni = 0; ni < 4; ++ni)
        acc[mi][ni] = mfma_mx(af, bf[ni], acc[mi][ni]);
      __builtin_amdgcn_s_setprio(0);
    }

    __builtin_amdgcn_sched_barrier(0);      // no ds_read may sink below
    __syncthreads();                        // all reads done; buffer free
  }

  // ---- fold phase 1: per-lane key top-2 of 4 cols -> LDS [128][34] uint2 --
  uint2* mrg = (uint2*)smem;
  const int slot = wn * 16 + lr;

  float cnv[4];
#pragma unroll
  for (int ni = 0; ni < 4; ++ni) cnv[ni] = cn[c0 + wn * 64 + ni * 16 + lr];

#pragma unroll
  for (int mi = 0; mi < 4; ++mi) {
#pragma unroll
    for (int r = 0; r < 4; ++r) {
      uint32_t k1 = 0xFFFFFFFFu, k2 = 0xFFFFFFFFu;
#pragma unroll
      for (int ni = 0; ni < 4; ++ni) {
        const float s = fmaf(-2.0f, acc[mi][ni][r], cnv[ni]);
        const uint32_t k = packkey(s, c0 + wn * 64 + ni * 16 + lr);
        if (k < k1) { k2 = k1; k1 = k; } else if (k < k2) { k2 = k; }
      }
      const int row = wm * 64 + mi * 16 + lg * 4 + r;
      uint2 e; e.x = k1; e.y = k2;
      mrg[row * 34 + slot] = e;
    }
  }
  __syncthreads();

  // ---- fold phase 2: (row, half) thread scans 32 keys, cross-half merge ---
  {
    const int row = tid >> 1, h = tid & 1;
    const uint4* mp = (const uint4*)(mrg + row * 34 + h * 16);
    uint32_t k1 = 0xFFFFFFFFu, k2 = 0xFFFFFFFFu;
#pragma unroll
    for (int j = 0; j < 8; ++j) {
      const uint4 v = mp[j];
      uint32_t a = (k1 < v.x) ? k1 : v.x;
      uint32_t b0 = (k1 < v.x) ? v.x : k1;
      uint32_t c = (k2 < v.y) ? k2 : v.y;
      k1 = a; k2 = (b0 < c) ? b0 : c;
      a = (k1 < v.z) ? k1 : v.z;
      b0 = (k1 < v.z) ? v.z : k1;
      c = (k2 < v.w) ? k2 : v.w;
      k1 = a; k2 = (b0 < c) ? b0 : c;
    }
    const uint32_t o1 = (uint32_t)__shfl_xor((int)k1, 1, 64);
    const uint32_t o2 = (uint32_t)__shfl_xor((int)k2, 1, 64);
    const uint32_t m1 = (k1 < o1) ? k1 : o1;
    const uint32_t hi = (k1 < o1) ? o1 : k1;
    const uint32_t lo2 = (k2 < o2) ? k2 : o2;
    const uint32_t m2 = (hi < lo2) ? hi : lo2;
    if (h == 0) {
      uint2 o; o.x = m1; o.y = m2;
      *((uint2*)(cand2 + ((size_t)(r0 + row) * 64 + nb) * 2)) = o;
    }
  }
#undef STAGE
#undef LDFRAG
}

// ---------------------------------------------------------------------------
// K5: top-select + exact fp32 rescore on packed keys. One wave per row;
// lane l holds nb=l's 2 keys. Margin 36 (32 validated + 4 key-quant slack).
// Fast path when exactly one candidate in margin.
// ---------------------------------------------------------------------------
__global__ __launch_bounds__(256) void rescore_kernel(
    const float* __restrict__ x, const float* __restrict__ cb,
    const uint32_t* __restrict__ cand2, int* __restrict__ idx_ws,
    float* __restrict__ out) {
  const int row = blockIdx.x * 4 + (threadIdx.x >> 6);
  const int l = threadIdx.x & 63;
  if (row == 0 && l == 0) out[(size_t)MROWS * DDIM + MROWS] = 0.0f;

  const uint2 pr = ((const uint2*)cand2)[(size_t)row * 64 + l];
  const uint32_t k1 = pr.x, k2 = pr.y;

  uint32_t bs = k1;
#pragma unroll
  for (int off = 1; off < 64; off <<= 1) {
    const uint32_t ob = (uint32_t)__shfl_xor((int)bs, off, 64);
    bs = (ob < bs) ? ob : bs;
  }
  const float smin = unpackkey(bs);
  const uint32_t thrkey = packkey(smin + 36.0f, 8191);
  unsigned long long mA = __ballot(k1 <= thrkey);
  unsigned long long mB = __ballot(k2 <= thrkey);

  if (__popcll(mA) + __popcll(mB) == 1) {
    if (l == 0) {
      const int code = (int)(bs & 8191u);
      idx_ws[row] = code;
      out[(size_t)MROWS * DDIM + row] = (float)code;
    }
    return;
  }

  const float4* x4 = (const float4*)(x + (size_t)row * DDIM);
  float4 xv[4];
#pragma unroll
  for (int i = 0; i < 4; ++i) xv[i] = x4[i * 64 + l];

  float bestS = __builtin_inff(); int bestI = KCODES;
#pragma unroll 1
  for (int half = 0; half < 2; ++half) {
    unsigned long long m = half ? mB : mA;
    const uint32_t myk = half ? k2 : k1;
    while (m) {
      const int b = __builtin_ctzll(m);
      m &= m - 1;
      const int code = __shfl((int)myk, b, 64) & 8191;
      const float4* c4 = (const float4*)(cb + (size_t)code * DDIM);
      float dot = 0.f, nn = 0.f;
#pragma unroll
      for (int i = 0; i < 4; ++i) {
        const float4 cv = c4[i * 64 + l];
        dot = fmaf(xv[i].x, cv.x, dot); dot = fmaf(xv[i].y, cv.y, dot);
        dot = fmaf(xv[i].z, cv.z, dot); dot = fmaf(xv[i].w, cv.w, dot);
        nn  = fmaf(cv.x, cv.x, nn);     nn  = fmaf(cv.y, cv.y, nn);
        nn  = fmaf(cv.z, cv.z, nn);     nn  = fmaf(cv.w, cv.w, nn);
      }
#pragma unroll
      for (int off = 32; off > 0; off >>= 1) {
        dot += __shfl_xor(dot, off, 64);
        nn  += __shfl_xor(nn,  off, 64);
      }
      const float sc = nn - 2.0f * dot;
      if (sc < bestS || (sc == bestS && code < bestI)) { bestS = sc; bestI = code; }
    }
  }
  if (l == 0) {
    idx_ws[row] = bestI;
    out[(size_t)MROWS * DDIM + row] = (float)bestI;
  }
}

// ---------------------------------------------------------------------------
// K6/K7: bf16 GEMM C = A[M][K] * B[N][K]^T (+bias). EPI==1: relu->bf16.
// EPI==2: f32 store.
// ---------------------------------------------------------------------------
template <int EPI>
__global__ __launch_bounds__(256) void gemm_bt_kernel(
    const unsigned short* __restrict__ A, const unsigned short* __restrict__ B,
    const float* __restrict__ bias, void* __restrict__ outp,
    int Nsize, int Kred, int nblk) {
  __shared__ unsigned short As[128 * 32];
  __shared__ unsigned short Bs[128 * 32];
  const int tid = threadIdx.x;
  const int l = tid & 63, w = tid >> 6;
  const int lr = l & 15, lg = l >> 4;
  const int wm = w >> 1, wn = w & 1;
  const int mb = blockIdx.x / nblk, nb = blockIdx.x % nblk;
  const int r0 = mb * 128, c0 = nb * 128;
  const int prow = tid >> 2, pcol = (tid & 3) * 8;

  f32x4 acc[4][4];
#pragma unroll
  for (int mi = 0; mi < 4; ++mi)
#pragma unroll
    for (int ni = 0; ni < 4; ++ni) acc[mi][ni] = 0.0f;

  const size_t aoff0 = (size_t)(r0 + prow) * Kred + pcol;
  const size_t aoff1 = aoff0 + (size_t)64 * Kred;
  const size_t boff0 = (size_t)(c0 + prow) * Kred + pcol;
  const size_t boff1 = boff0 + (size_t)64 * Kred;

  const int nks = Kred >> 5;
  for (int ks = 0; ks < nks; ++ks) {
    const int k0 = ks * 32;
    gload_lds16(A + aoff0 + k0, &As[tid * 8]);
    gload_lds16(A + aoff1 + k0, &As[2048 + tid * 8]);
    gload_lds16(B + boff0 + k0, &Bs[tid * 8]);
    gload_lds16(B + boff1 + k0, &Bs[2048 + tid * 8]);
    __syncthreads();

    bf16x8 af[4], bfv[4];
#pragma unroll
    for (int mi = 0; mi < 4; ++mi)
      af[mi] = *reinterpret_cast<const bf16x8*>(
          &As[(wm * 64 + mi * 16 + lr) * 32 + lg * 8]);
#pragma unroll
    for (int ni = 0; ni < 4; ++ni)
      bfv[ni] = *reinterpret_cast<const bf16x8*>(
          &Bs[(wn * 64 + ni * 16 + lr) * 32 + lg * 8]);
#pragma unroll
    for (int mi = 0; mi < 4; ++mi)
#pragma unroll
      for (int ni = 0; ni < 4; ++ni)
        acc[mi][ni] = __builtin_amdgcn_mfma_f32_16x16x32_bf16(
            af[mi], bfv[ni], acc[mi][ni], 0, 0, 0);
    __syncthreads();
  }

#pragma unroll
  for (int ni = 0; ni < 4; ++ni) {
    const int col = c0 + wn * 64 + ni * 16 + lr;
    const float bv = bias[col];
#pragma unroll
    for (int mi = 0; mi < 4; ++mi) {
#pragma unroll
      for (int r = 0; r < 4; ++r) {
        const int row = r0 + wm * 64 + mi * 16 + lg * 4 + r;
        const float v = acc[mi][ni][r] + bv;
        if (EPI == 1) {
          ((unsigned short*)outp)[(size_t)row * Nsize + col] =
              f2bf(fmaxf(v, 0.0f));
        } else {
          ((float*)outp)[(size_t)row * Nsize + col] = v;
        }
      }
    }
  }
}

// ---------------------------------------------------------------------------
// K8: recon[row] = dec[idx[row]] gather-write + fused commitment loss.
// ---------------------------------------------------------------------------
__global__ __launch_bounds__(256) void epilogue_kernel(
    const float* __restrict__ x, const float* __restrict__ cb,
    const float* __restrict__ dec, const int* __restrict__ idx_ws,
    float* __restrict__ out) {
  __shared__ float wsum[4];
  const int r = blockIdx.x, t = threadIdx.x;
  const int code = idx_ws[r];
  const float4 dv = ((const float4*)(dec + (size_t)code * DDIM))[t];
  ((float4*)(out + (size_t)r * DDIM))[t] = dv;
  const float4 xv = ((const float4*)(x + (size_t)r * DDIM))[t];
  const float4 cv = ((const float4*)(cb + (size_t)code * DDIM))[t];
  const float ex = xv.x - cv.x, ey = xv.y - cv.y;
  const float ez = xv.z - cv.z, ew = xv.w - cv.w;
  float pr = ex * ex + ey * ey + ez * ez + ew * ew;
  pr = waveReduceSum(pr);
  if ((t & 63) == 0) wsum[t >> 6] = pr;
  __syncthreads();
  if (t == 0) {
    const float total = wsum[0] + wsum[1] + wsum[2] + wsum[3];
    atomicAdd(out + (size_t)MROWS * DDIM + MROWS, total * (0.25f / 16777216.0f));
  }
}

// ---------------------------------------------------------------------------
extern "C" void kernel_launch(void* const* d_in, const int* in_sizes, int n_in,
                              void* d_out, int out_size, void* d_ws,
                              size_t ws_size, hipStream_t stream) {
  const float* features = (const float*)d_in[0];  // [8,2048,1024]
  const float* codebook = (const float*)d_in[1];  // [8192,1024]
  const float* w1 = (const float*)d_in[2];        // [1024,512]
  const float* b1 = (const float*)d_in[3];        // [512]
  const float* w2 = (const float*)d_in[4];        // [512,1024]
  const float* b2 = (const float*)d_in[5];        // [1024]
  float* out = (float*)d_out;
  char* ws = (char*)d_ws;

  uint8_t*        xq8 = (uint8_t*)(ws + 0);                // 16,777,216
  uint8_t*        cq8 = (uint8_t*)(ws + 16777216);         //  8,388,608
  unsigned short* cbb = (unsigned short*)(ws + 25165824);  // 16,777,216
  float*          cn  = (float*)(ws + 41943040);           //     32,768
  unsigned short* w1t = (unsigned short*)(ws + 41975808);  //  1,048,576
  unsigned short* w2t = (unsigned short*)(ws + 43024384);  //  1,048,576
  unsigned short* hb  = (unsigned short*)(ws + 44072960);  //  8,388,608
  float*          dec = (float*)(ws + 52461568);           // 33,554,432
  int*            idxw = (int*)(ws + 86016000);            //     65,536
  // cand2 (8 MB) aliases dec: consumed by rescore BEFORE gemm<2> writes dec
  // (stream-ordered -> safe).
  uint32_t*       cand2 = (uint32_t*)(ws + 52461568);

  prep_kernel<<<17408, 256, 0, stream>>>(features, codebook, w1, w2,
                                         xq8, cq8, cbb, cn, w1t, w2t);

  coarse_kernel<<<(MROWS / 128) * (KCODES / 128), 256, 0, stream>>>(
      xq8, cq8, cn, cand2);
  rescore_kernel<<<MROWS / 4, 256, 0, stream>>>(features, codebook, cand2,
                                                idxw, out);

  // decode the codebook (8192 rows), then recon = dec[idx]
  gemm_bt_kernel<1><<<64 * (HDIM / 128), 256, 0, stream>>>(
      cbb, w1t, b1, hb, HDIM, DDIM, HDIM / 128);
  gemm_bt_kernel<2><<<64 * (DDIM / 128), 256, 0, stream>>>(
      hb, w2t, b2, dec, DDIM, HDIM, DDIM / 128);

  epilogue_kernel<<<MROWS, 256, 0, stream>>>(features, codebook, dec, idxw, out);
}

// Round 12
// 315.640 us; speedup vs baseline: 2.5893x; 1.5675x over previous
//
#include <hip/hip_runtime.h>
#include <hip/hip_fp8.h>
#include <stdint.h>

// ---------------------------------------------------------------------------
// VQ-VAE quantizer. R12: epilogue rebuilt -- 8 rows/block (ILP + TLP), loss
// via per-block partials in ws + deterministic 1-block reduce (no global
// atomics). Coarse/rescore/prep/gemms frozen from R11 (validated).
// Sizes: M=B*T=16384, D=1024, K=8192 codes, H=512.
// ---------------------------------------------------------------------------

#define MROWS  16384
#define DDIM   1024
#define KCODES 8192
#define HDIM   512

typedef __attribute__((ext_vector_type(4))) float  f32x4;
typedef __attribute__((ext_vector_type(8))) __bf16 bf16x8;
typedef __attribute__((ext_vector_type(4))) int    i32x4;
typedef __attribute__((ext_vector_type(8))) int    i32x8;

__device__ __forceinline__ unsigned short f2bf(float f) {
  uint32_t b = __float_as_uint(f);
  b += 0x7FFFu + ((b >> 16) & 1u);          // RNE
  return (unsigned short)(b >> 16);
}

__device__ __forceinline__ uint32_t f2fp8(float f) {
  return (uint32_t)__hip_fp8_e4m3(f).__x;   // OCP e4m3fn, saturating
}

// sortable key: monotonic-f32 top 19 bits | idx (13 bits).
__device__ __forceinline__ uint32_t packkey(float s, int idx) {
  uint32_t u = __float_as_uint(s);
  u = ((int)u < 0) ? ~u : (u | 0x80000000u);
  return (u & 0xFFFFE000u) | (uint32_t)idx;
}
__device__ __forceinline__ float unpackkey(uint32_t k) {
  uint32_t u = k & 0xFFFFE000u;
  u = (u & 0x80000000u) ? (u ^ 0x80000000u) : ~u;
  return __uint_as_float(u);   // floor: result <= true score
}

__device__ __forceinline__ void gload_lds16(const void* g, void* l) {
  __builtin_amdgcn_global_load_lds(
      (__attribute__((address_space(1))) void*)(uintptr_t)g,
      (__attribute__((address_space(3))) void*)(uint32_t)(uintptr_t)l,
      16, 0, 0);
}

__device__ __forceinline__ f32x4 mfma_mx(i32x8 a, i32x8 b, f32x4 c) {
  return __builtin_amdgcn_mfma_scale_f32_16x16x128_f8f6f4(
      a, b, c, 0, 0, 0, 0x7F7F7F7F, 0, 0x7F7F7F7F);
}

__device__ __forceinline__ float waveReduceSum(float v) {
#pragma unroll
  for (int off = 32; off > 0; off >>= 1) v += __shfl_xor(v, off, 64);
  return v;
}

// ---------------------------------------------------------------------------
// K0: fused prep. [0,8192): features f32->fp8; [8192,16384): codebook ->
// bf16 + fp8 + norm; [16384,16896): w1^T 32x32 LDS tiles; [16896,17408): w2^T.
// ---------------------------------------------------------------------------
__global__ __launch_bounds__(256) void prep_kernel(
    const float* __restrict__ features, const float* __restrict__ codebook,
    const float* __restrict__ w1, const float* __restrict__ w2,
    uint8_t* __restrict__ xq8, uint8_t* __restrict__ cq8,
    unsigned short* __restrict__ cbb, float* __restrict__ cn,
    unsigned short* __restrict__ w1t, unsigned short* __restrict__ w2t) {
  __shared__ float wsum[4];
  __shared__ float tile[32][33];
  const int bid = blockIdx.x, t = threadIdx.x;
  if (bid < 8192) {
    const int id = bid * 256 + t;
    const float4 v0 = ((const float4*)features)[id * 2];
    const float4 v1 = ((const float4*)features)[id * 2 + 1];
    uint2 u;
    u.x = f2fp8(v0.x) | (f2fp8(v0.y) << 8) | (f2fp8(v0.z) << 16) |
          (f2fp8(v0.w) << 24);
    u.y = f2fp8(v1.x) | (f2fp8(v1.y) << 8) | (f2fp8(v1.z) << 16) |
          (f2fp8(v1.w) << 24);
    ((uint2*)xq8)[id] = u;
  } else if (bid < 16384) {
    const int k = bid - 8192;
    const float4 v = ((const float4*)(codebook + (size_t)k * DDIM))[t];
    ushort4 u;
    u.x = f2bf(v.x); u.y = f2bf(v.y); u.z = f2bf(v.z); u.w = f2bf(v.w);
    ((ushort4*)(cbb + (size_t)k * DDIM))[t] = u;
    const uint32_t p8 = f2fp8(v.x) | (f2fp8(v.y) << 8) | (f2fp8(v.z) << 16) |
                        (f2fp8(v.w) << 24);
    ((uint32_t*)(cq8 + (size_t)k * DDIM))[t] = p8;
    float p = v.x * v.x + v.y * v.y + v.z * v.z + v.w * v.w;
    p = waveReduceSum(p);
    if ((t & 63) == 0) wsum[t >> 6] = p;
    __syncthreads();
    if (t == 0) cn[k] = wsum[0] + wsum[1] + wsum[2] + wsum[3];
  } else {
    // LDS-tiled transpose f32[R][C] -> bf16[C][R], 32x32 tiles
    const float* src;
    unsigned short* dst;
    int R, C, t32;
    if (bid < 16896) { src = w1; dst = w1t; R = 1024; C = 512;
                       t32 = bid - 16384; }
    else             { src = w2; dst = w2t; R = 512;  C = 1024;
                       t32 = bid - 16896; }
    const int nct = C / 32;
    const int tr0 = (t32 / nct) * 32, tc0 = (t32 % nct) * 32;
    const int rr = t >> 3, cc = (t & 7) * 4;
    const float4 v = *(const float4*)(src + (size_t)(tr0 + rr) * C + tc0 + cc);
    tile[rr][cc + 0] = v.x; tile[rr][cc + 1] = v.y;
    tile[rr][cc + 2] = v.z; tile[rr][cc + 3] = v.w;
    __syncthreads();
    ushort4 o;
    o.x = f2bf(tile[cc + 0][rr]); o.y = f2bf(tile[cc + 1][rr]);
    o.z = f2bf(tile[cc + 2][rr]); o.w = f2bf(tile[cc + 3][rr]);
    *(ushort4*)(dst + (size_t)(tc0 + rr) * R + tr0 + cc) = o;
  }
}

// ---------------------------------------------------------------------------
// K4: coarse scores = cn[k] - 2 * (xq . cq) via MX-fp8 MFMA (K=128).
// 128x128 tile, 4 waves (2x2), 8 K-tiles, single-buffer LDS 32KB.
// Fold: packed keys -> LDS transpose 2-phase -> cand2[row][nb] top-2 keys.
// (Frozen from R11.)
// ---------------------------------------------------------------------------
__global__ __launch_bounds__(256, 3) void coarse_kernel(
    const uint8_t* __restrict__ xq,   // [MROWS][DDIM] fp8
    const uint8_t* __restrict__ cq,   // [KCODES][DDIM] fp8
    const float* __restrict__ cn,     // [KCODES]
    uint32_t* __restrict__ cand2)     // [MROWS][64][2] keys
{
  __shared__ char smem[34816];   // main: 32KB (A16+B16); fold: 128x34 uint2

  const int tid = threadIdx.x;
  const int l = tid & 63, w = tid >> 6;
  const int lr = l & 15, lg = l >> 4;
  const int wm = w >> 1, wn = w & 1;

  // bijective XCD swizzle (nwg = 8192 = 8 * 1024)
  const int bid = blockIdx.x;
  const int swz = (bid & 7) * 1024 + (bid >> 3);
  const int mb = swz >> 6, nb = swz & 63;
  const int r0 = mb * 128, c0 = nb * 128;

  const int scolb = ((tid & 7) * 16) ^ (((tid >> 3) & 7) << 4);
  const uint8_t* aSrc = xq + (size_t)(r0 + (tid >> 3)) * DDIM + scolb;
  const uint8_t* bSrc = cq + (size_t)(c0 + (tid >> 3)) * DDIM + scolb;
  const int dBase = tid * 16;

  const int sxor = (lr & 7) << 4;
  const int kLo = (lg * 32) ^ sxor;
  const int kHi = (lg * 32 + 16) ^ sxor;
  const int aRow = (wm * 64 + lr) * 128;            // + mi*2048
  const int bRow = 16384 + (wn * 64 + lr) * 128;    // + ni*2048

#define STAGE(KT)                                                             \
  {                                                                           \
    _Pragma("unroll")                                                         \
    for (int j = 0; j < 4; ++j)                                               \
      gload_lds16(aSrc + (size_t)j * 32 * DDIM + (KT) * 128,                  \
                  smem + dBase + j * 4096);                                   \
    _Pragma("unroll")                                                         \
    for (int j = 0; j < 4; ++j)                                               \
      gload_lds16(bSrc + (size_t)j * 32 * DDIM + (KT) * 128,                  \
                  smem + 16384 + dBase + j * 4096);                           \
  }

#define LDFRAG(dst, off)                                                      \
  {                                                                           \
    i32x4 _lo = *(const i32x4*)(smem + (off) + kLo);                          \
    i32x4 _hi = *(const i32x4*)(smem + (off) + kHi);                          \
    dst = __builtin_shufflevector(_lo, _hi, 0, 1, 2, 3, 4, 5, 6, 7);          \
  }

  f32x4 acc[4][4];
#pragma unroll
  for (int mi = 0; mi < 4; ++mi)
#pragma unroll
    for (int ni = 0; ni < 4; ++ni) acc[mi][ni] = 0.0f;

#pragma unroll 1
  for (int kt = 0; kt < 8; ++kt) {
    __builtin_amdgcn_sched_barrier(0);
    STAGE(kt)
    __builtin_amdgcn_sched_barrier(0);
    __syncthreads();                        // loads landed (vmcnt drained)

    i32x8 bf[4];
#pragma unroll
    for (int ni = 0; ni < 4; ++ni) LDFRAG(bf[ni], bRow + ni * 2048)
#pragma unroll
    for (int mi = 0; mi < 4; ++mi) {
      i32x8 af;
      LDFRAG(af, aRow + mi * 2048)
      __builtin_amdgcn_s_setprio(1);
#pragma unroll
      for (int ni = 0; ni < 4; ++ni)
        acc[mi][ni] = mfma_mx(af, bf[ni], acc[mi][ni]);
      __builtin_amdgcn_s_setprio(0);
    }

    __builtin_amdgcn_sched_barrier(0);      // no ds_read may sink below
    __syncthreads();                        // all reads done; buffer free
  }

  // ---- fold phase 1: per-lane key top-2 of 4 cols -> LDS [128][34] uint2 --
  uint2* mrg = (uint2*)smem;
  const int slot = wn * 16 + lr;

  float cnv[4];
#pragma unroll
  for (int ni = 0; ni < 4; ++ni) cnv[ni] = cn[c0 + wn * 64 + ni * 16 + lr];

#pragma unroll
  for (int mi = 0; mi < 4; ++mi) {
#pragma unroll
    for (int r = 0; r < 4; ++r) {
      uint32_t k1 = 0xFFFFFFFFu, k2 = 0xFFFFFFFFu;
#pragma unroll
      for (int ni = 0; ni < 4; ++ni) {
        const float s = fmaf(-2.0f, acc[mi][ni][r], cnv[ni]);
        const uint32_t k = packkey(s, c0 + wn * 64 + ni * 16 + lr);
        if (k < k1) { k2 = k1; k1 = k; } else if (k < k2) { k2 = k; }
      }
      const int row = wm * 64 + mi * 16 + lg * 4 + r;
      uint2 e; e.x = k1; e.y = k2;
      mrg[row * 34 + slot] = e;
    }
  }
  __syncthreads();

  // ---- fold phase 2: (row, half) thread scans 32 keys, cross-half merge ---
  {
    const int row = tid >> 1, h = tid & 1;
    const uint4* mp = (const uint4*)(mrg + row * 34 + h * 16);
    uint32_t k1 = 0xFFFFFFFFu, k2 = 0xFFFFFFFFu;
#pragma unroll
    for (int j = 0; j < 8; ++j) {
      const uint4 v = mp[j];
      uint32_t a = (k1 < v.x) ? k1 : v.x;
      uint32_t b0 = (k1 < v.x) ? v.x : k1;
      uint32_t c = (k2 < v.y) ? k2 : v.y;
      k1 = a; k2 = (b0 < c) ? b0 : c;
      a = (k1 < v.z) ? k1 : v.z;
      b0 = (k1 < v.z) ? v.z : k1;
      c = (k2 < v.w) ? k2 : v.w;
      k1 = a; k2 = (b0 < c) ? b0 : c;
    }
    const uint32_t o1 = (uint32_t)__shfl_xor((int)k1, 1, 64);
    const uint32_t o2 = (uint32_t)__shfl_xor((int)k2, 1, 64);
    const uint32_t m1 = (k1 < o1) ? k1 : o1;
    const uint32_t hi = (k1 < o1) ? o1 : k1;
    const uint32_t lo2 = (k2 < o2) ? k2 : o2;
    const uint32_t m2 = (hi < lo2) ? hi : lo2;
    if (h == 0) {
      uint2 o; o.x = m1; o.y = m2;
      *((uint2*)(cand2 + ((size_t)(r0 + row) * 64 + nb) * 2)) = o;
    }
  }
#undef STAGE
#undef LDFRAG
}

// ---------------------------------------------------------------------------
// K5: top-select + exact fp32 rescore on packed keys (frozen from R11).
// ---------------------------------------------------------------------------
__global__ __launch_bounds__(256) void rescore_kernel(
    const float* __restrict__ x, const float* __restrict__ cb,
    const uint32_t* __restrict__ cand2, int* __restrict__ idx_ws,
    float* __restrict__ out) {
  const int row = blockIdx.x * 4 + (threadIdx.x >> 6);
  const int l = threadIdx.x & 63;

  const uint2 pr = ((const uint2*)cand2)[(size_t)row * 64 + l];
  const uint32_t k1 = pr.x, k2 = pr.y;

  uint32_t bs = k1;
#pragma unroll
  for (int off = 1; off < 64; off <<= 1) {
    const uint32_t ob = (uint32_t)__shfl_xor((int)bs, off, 64);
    bs = (ob < bs) ? ob : bs;
  }
  const float smin = unpackkey(bs);
  const uint32_t thrkey = packkey(smin + 36.0f, 8191);
  unsigned long long mA = __ballot(k1 <= thrkey);
  unsigned long long mB = __ballot(k2 <= thrkey);

  if (__popcll(mA) + __popcll(mB) == 1) {
    if (l == 0) {
      const int code = (int)(bs & 8191u);
      idx_ws[row] = code;
      out[(size_t)MROWS * DDIM + row] = (float)code;
    }
    return;
  }

  const float4* x4 = (const float4*)(x + (size_t)row * DDIM);
  float4 xv[4];
#pragma unroll
  for (int i = 0; i < 4; ++i) xv[i] = x4[i * 64 + l];

  float bestS = __builtin_inff(); int bestI = KCODES;
#pragma unroll 1
  for (int half = 0; half < 2; ++half) {
    unsigned long long m = half ? mB : mA;
    const uint32_t myk = half ? k2 : k1;
    while (m) {
      const int b = __builtin_ctzll(m);
      m &= m - 1;
      const int code = __shfl((int)myk, b, 64) & 8191;
      const float4* c4 = (const float4*)(cb + (size_t)code * DDIM);
      float dot = 0.f, nn = 0.f;
#pragma unroll
      for (int i = 0; i < 4; ++i) {
        const float4 cv = c4[i * 64 + l];
        dot = fmaf(xv[i].x, cv.x, dot); dot = fmaf(xv[i].y, cv.y, dot);
        dot = fmaf(xv[i].z, cv.z, dot); dot = fmaf(xv[i].w, cv.w, dot);
        nn  = fmaf(cv.x, cv.x, nn);     nn  = fmaf(cv.y, cv.y, nn);
        nn  = fmaf(cv.z, cv.z, nn);     nn  = fmaf(cv.w, cv.w, nn);
      }
#pragma unroll
      for (int off = 32; off > 0; off >>= 1) {
        dot += __shfl_xor(dot, off, 64);
        nn  += __shfl_xor(nn,  off, 64);
      }
      const float sc = nn - 2.0f * dot;
      if (sc < bestS || (sc == bestS && code < bestI)) { bestS = sc; bestI = code; }
    }
  }
  if (l == 0) {
    idx_ws[row] = bestI;
    out[(size_t)MROWS * DDIM + row] = (float)bestI;
  }
}

// ---------------------------------------------------------------------------
// K6/K7: bf16 GEMM C = A[M][K] * B[N][K]^T (+bias). EPI==1: relu->bf16.
// EPI==2: f32 store.
// ---------------------------------------------------------------------------
template <int EPI>
__global__ __launch_bounds__(256) void gemm_bt_kernel(
    const unsigned short* __restrict__ A, const unsigned short* __restrict__ B,
    const float* __restrict__ bias, void* __restrict__ outp,
    int Nsize, int Kred, int nblk) {
  __shared__ unsigned short As[128 * 32];
  __shared__ unsigned short Bs[128 * 32];
  const int tid = threadIdx.x;
  const int l = tid & 63, w = tid >> 6;
  const int lr = l & 15, lg = l >> 4;
  const int wm = w >> 1, wn = w & 1;
  const int mb = blockIdx.x / nblk, nb = blockIdx.x % nblk;
  const int r0 = mb * 128, c0 = nb * 128;
  const int prow = tid >> 2, pcol = (tid & 3) * 8;

  f32x4 acc[4][4];
#pragma unroll
  for (int mi = 0; mi < 4; ++mi)
#pragma unroll
    for (int ni = 0; ni < 4; ++ni) acc[mi][ni] = 0.0f;

  const size_t aoff0 = (size_t)(r0 + prow) * Kred + pcol;
  const size_t aoff1 = aoff0 + (size_t)64 * Kred;
  const size_t boff0 = (size_t)(c0 + prow) * Kred + pcol;
  const size_t boff1 = boff0 + (size_t)64 * Kred;

  const int nks = Kred >> 5;
  for (int ks = 0; ks < nks; ++ks) {
    const int k0 = ks * 32;
    gload_lds16(A + aoff0 + k0, &As[tid * 8]);
    gload_lds16(A + aoff1 + k0, &As[2048 + tid * 8]);
    gload_lds16(B + boff0 + k0, &Bs[tid * 8]);
    gload_lds16(B + boff1 + k0, &Bs[2048 + tid * 8]);
    __syncthreads();

    bf16x8 af[4], bfv[4];
#pragma unroll
    for (int mi = 0; mi < 4; ++mi)
      af[mi] = *reinterpret_cast<const bf16x8*>(
          &As[(wm * 64 + mi * 16 + lr) * 32 + lg * 8]);
#pragma unroll
    for (int ni = 0; ni < 4; ++ni)
      bfv[ni] = *reinterpret_cast<const bf16x8*>(
          &Bs[(wn * 64 + ni * 16 + lr) * 32 + lg * 8]);
#pragma unroll
    for (int mi = 0; mi < 4; ++mi)
#pragma unroll
      for (int ni = 0; ni < 4; ++ni)
        acc[mi][ni] = __builtin_amdgcn_mfma_f32_16x16x32_bf16(
            af[mi], bfv[ni], acc[mi][ni], 0, 0, 0);
    __syncthreads();
  }

#pragma unroll
  for (int ni = 0; ni < 4; ++ni) {
    const int col = c0 + wn * 64 + ni * 16 + lr;
    const float bv = bias[col];
#pragma unroll
    for (int mi = 0; mi < 4; ++mi) {
#pragma unroll
      for (int r = 0; r < 4; ++r) {
        const int row = r0 + wm * 64 + mi * 16 + lg * 4 + r;
        const float v = acc[mi][ni][r] + bv;
        if (EPI == 1) {
          ((unsigned short*)outp)[(size_t)row * Nsize + col] =
              f2bf(fmaxf(v, 0.0f));
        } else {
          ((float*)outp)[(size_t)row * Nsize + col] = v;
        }
      }
    }
  }
}

// ---------------------------------------------------------------------------
// K8: recon gather + loss partials. 8 rows/block (ILP); per-block partial
// to ws (NO global atomics).
// ---------------------------------------------------------------------------
__global__ __launch_bounds__(256) void epilogue_kernel(
    const float* __restrict__ x, const float* __restrict__ cb,
    const float* __restrict__ dec, const int* __restrict__ idx_ws,
    float* __restrict__ out, float* __restrict__ partial) {
  __shared__ float wsum[4];
  const int t = threadIdx.x;
  const int base = blockIdx.x * 8;

  int code[8];
#pragma unroll
  for (int rr = 0; rr < 8; ++rr) code[rr] = idx_ws[base + rr];

  float lsum = 0.0f;
#pragma unroll
  for (int rr = 0; rr < 8; ++rr) {
    const int r = base + rr;
    const float4 dv = ((const float4*)(dec + (size_t)code[rr] * DDIM))[t];
    ((float4*)(out + (size_t)r * DDIM))[t] = dv;
    const float4 xv = ((const float4*)(x + (size_t)r * DDIM))[t];
    const float4 cv = ((const float4*)(cb + (size_t)code[rr] * DDIM))[t];
    const float ex = xv.x - cv.x, ey = xv.y - cv.y;
    const float ez = xv.z - cv.z, ew = xv.w - cv.w;
    lsum += ex * ex + ey * ey + ez * ez + ew * ew;
  }
  lsum = waveReduceSum(lsum);
  if ((t & 63) == 0) wsum[t >> 6] = lsum;
  __syncthreads();
  if (t == 0)
    partial[blockIdx.x] = wsum[0] + wsum[1] + wsum[2] + wsum[3];
}

// ---------------------------------------------------------------------------
// K9: deterministic final loss reduce over 2048 partials.
// ---------------------------------------------------------------------------
__global__ __launch_bounds__(256) void loss_reduce_kernel(
    const float* __restrict__ partial, float* __restrict__ out) {
  __shared__ float wsum[4];
  const int t = threadIdx.x;
  float s = 0.0f;
#pragma unroll
  for (int j = 0; j < 8; ++j) s += partial[t * 8 + j];
  s = waveReduceSum(s);
  if ((t & 63) == 0) wsum[t >> 6] = s;
  __syncthreads();
  if (t == 0) {
    const float total = wsum[0] + wsum[1] + wsum[2] + wsum[3];
    // 0.25 / 16777216 is a power-of-two scale: exact
    out[(size_t)MROWS * DDIM + MROWS] = total * (0.25f / 16777216.0f);
  }
}

// ---------------------------------------------------------------------------
extern "C" void kernel_launch(void* const* d_in, const int* in_sizes, int n_in,
                              void* d_out, int out_size, void* d_ws,
                              size_t ws_size, hipStream_t stream) {
  const float* features = (const float*)d_in[0];  // [8,2048,1024]
  const float* codebook = (const float*)d_in[1];  // [8192,1024]
  const float* w1 = (const float*)d_in[2];        // [1024,512]
  const float* b1 = (const float*)d_in[3];        // [512]
  const float* w2 = (const float*)d_in[4];        // [512,1024]
  const float* b2 = (const float*)d_in[5];        // [1024]
  float* out = (float*)d_out;
  char* ws = (char*)d_ws;

  uint8_t*        xq8 = (uint8_t*)(ws + 0);                // 16,777,216
  uint8_t*        cq8 = (uint8_t*)(ws + 16777216);         //  8,388,608
  unsigned short* cbb = (unsigned short*)(ws + 25165824);  // 16,777,216
  float*          cn  = (float*)(ws + 41943040);           //     32,768
  unsigned short* w1t = (unsigned short*)(ws + 41975808);  //  1,048,576
  unsigned short* w2t = (unsigned short*)(ws + 43024384);  //  1,048,576
  unsigned short* hb  = (unsigned short*)(ws + 44072960);  //  8,388,608
  float*          dec = (float*)(ws + 52461568);           // 33,554,432
  int*            idxw = (int*)(ws + 86016000);            //     65,536
  float*          lpart = (float*)(ws + 86081536);         //      8,192
  // cand2 (8 MB) aliases dec: consumed by rescore BEFORE gemm<2> writes dec
  // (stream-ordered -> safe).
  uint32_t*       cand2 = (uint32_t*)(ws + 52461568);

  prep_kernel<<<17408, 256, 0, stream>>>(features, codebook, w1, w2,
                                         xq8, cq8, cbb, cn, w1t, w2t);

  coarse_kernel<<<(MROWS / 128) * (KCODES / 128), 256, 0, stream>>>(
      xq8, cq8, cn, cand2);
  rescore_kernel<<<MROWS / 4, 256, 0, stream>>>(features, codebook, cand2,
                                                idxw, out);

  // decode the codebook (8192 rows), then recon = dec[idx]
  gemm_bt_kernel<1><<<64 * (HDIM / 128), 256, 0, stream>>>(
      cbb, w1t, b1, hb, HDIM, DDIM, HDIM / 128);
  gemm_bt_kernel<2><<<64 * (DDIM / 128), 256, 0, stream>>>(
      hb, w2t, b2, dec, DDIM, HDIM, DDIM / 128);

  epilogue_kernel<<<MROWS / 8, 256, 0, stream>>>(features, codebook, dec,
                                                 idxw, out, lpart);
  loss_reduce_kernel<<<1, 256, 0, stream>>>(lpart, out);
}

// Round 13
// 307.416 us; speedup vs baseline: 2.6585x; 1.0268x over previous
//
#include <hip/hip_runtime.h>
#include <hip/hip_fp8.h>
#include <stdint.h>

// ---------------------------------------------------------------------------
// VQ-VAE quantizer. R13: coarse gets an L2-blocked traversal (4mb x 8nb
// chunks per XCD -- bijective remap only, schedule frozen from R11/R12);
// epilogue widened to 16 rows/block. Everything else frozen.
// Sizes: M=B*T=16384, D=1024, K=8192 codes, H=512.
// ---------------------------------------------------------------------------

#define MROWS  16384
#define DDIM   1024
#define KCODES 8192
#define HDIM   512
#define EROWS  16

typedef __attribute__((ext_vector_type(4))) float  f32x4;
typedef __attribute__((ext_vector_type(8))) __bf16 bf16x8;
typedef __attribute__((ext_vector_type(4))) int    i32x4;
typedef __attribute__((ext_vector_type(8))) int    i32x8;

__device__ __forceinline__ unsigned short f2bf(float f) {
  uint32_t b = __float_as_uint(f);
  b += 0x7FFFu + ((b >> 16) & 1u);          // RNE
  return (unsigned short)(b >> 16);
}

__device__ __forceinline__ uint32_t f2fp8(float f) {
  return (uint32_t)__hip_fp8_e4m3(f).__x;   // OCP e4m3fn, saturating
}

// sortable key: monotonic-f32 top 19 bits | idx (13 bits).
__device__ __forceinline__ uint32_t packkey(float s, int idx) {
  uint32_t u = __float_as_uint(s);
  u = ((int)u < 0) ? ~u : (u | 0x80000000u);
  return (u & 0xFFFFE000u) | (uint32_t)idx;
}
__device__ __forceinline__ float unpackkey(uint32_t k) {
  uint32_t u = k & 0xFFFFE000u;
  u = (u & 0x80000000u) ? (u ^ 0x80000000u) : ~u;
  return __uint_as_float(u);   // floor: result <= true score
}

__device__ __forceinline__ void gload_lds16(const void* g, void* l) {
  __builtin_amdgcn_global_load_lds(
      (__attribute__((address_space(1))) void*)(uintptr_t)g,
      (__attribute__((address_space(3))) void*)(uint32_t)(uintptr_t)l,
      16, 0, 0);
}

__device__ __forceinline__ f32x4 mfma_mx(i32x8 a, i32x8 b, f32x4 c) {
  return __builtin_amdgcn_mfma_scale_f32_16x16x128_f8f6f4(
      a, b, c, 0, 0, 0, 0x7F7F7F7F, 0, 0x7F7F7F7F);
}

__device__ __forceinline__ float waveReduceSum(float v) {
#pragma unroll
  for (int off = 32; off > 0; off >>= 1) v += __shfl_xor(v, off, 64);
  return v;
}

// ---------------------------------------------------------------------------
// K0: fused prep. [0,8192): features f32->fp8; [8192,16384): codebook ->
// bf16 + fp8 + norm; [16384,16896): w1^T 32x32 LDS tiles; [16896,17408): w2^T.
// ---------------------------------------------------------------------------
__global__ __launch_bounds__(256) void prep_kernel(
    const float* __restrict__ features, const float* __restrict__ codebook,
    const float* __restrict__ w1, const float* __restrict__ w2,
    uint8_t* __restrict__ xq8, uint8_t* __restrict__ cq8,
    unsigned short* __restrict__ cbb, float* __restrict__ cn,
    unsigned short* __restrict__ w1t, unsigned short* __restrict__ w2t) {
  __shared__ float wsum[4];
  __shared__ float tile[32][33];
  const int bid = blockIdx.x, t = threadIdx.x;
  if (bid < 8192) {
    const int id = bid * 256 + t;
    const float4 v0 = ((const float4*)features)[id * 2];
    const float4 v1 = ((const float4*)features)[id * 2 + 1];
    uint2 u;
    u.x = f2fp8(v0.x) | (f2fp8(v0.y) << 8) | (f2fp8(v0.z) << 16) |
          (f2fp8(v0.w) << 24);
    u.y = f2fp8(v1.x) | (f2fp8(v1.y) << 8) | (f2fp8(v1.z) << 16) |
          (f2fp8(v1.w) << 24);
    ((uint2*)xq8)[id] = u;
  } else if (bid < 16384) {
    const int k = bid - 8192;
    const float4 v = ((const float4*)(codebook + (size_t)k * DDIM))[t];
    ushort4 u;
    u.x = f2bf(v.x); u.y = f2bf(v.y); u.z = f2bf(v.z); u.w = f2bf(v.w);
    ((ushort4*)(cbb + (size_t)k * DDIM))[t] = u;
    const uint32_t p8 = f2fp8(v.x) | (f2fp8(v.y) << 8) | (f2fp8(v.z) << 16) |
                        (f2fp8(v.w) << 24);
    ((uint32_t*)(cq8 + (size_t)k * DDIM))[t] = p8;
    float p = v.x * v.x + v.y * v.y + v.z * v.z + v.w * v.w;
    p = waveReduceSum(p);
    if ((t & 63) == 0) wsum[t >> 6] = p;
    __syncthreads();
    if (t == 0) cn[k] = wsum[0] + wsum[1] + wsum[2] + wsum[3];
  } else {
    // LDS-tiled transpose f32[R][C] -> bf16[C][R], 32x32 tiles
    const float* src;
    unsigned short* dst;
    int R, C, t32;
    if (bid < 16896) { src = w1; dst = w1t; R = 1024; C = 512;
                       t32 = bid - 16384; }
    else             { src = w2; dst = w2t; R = 512;  C = 1024;
                       t32 = bid - 16896; }
    const int nct = C / 32;
    const int tr0 = (t32 / nct) * 32, tc0 = (t32 % nct) * 32;
    const int rr = t >> 3, cc = (t & 7) * 4;
    const float4 v = *(const float4*)(src + (size_t)(tr0 + rr) * C + tc0 + cc);
    tile[rr][cc + 0] = v.x; tile[rr][cc + 1] = v.y;
    tile[rr][cc + 2] = v.z; tile[rr][cc + 3] = v.w;
    __syncthreads();
    ushort4 o;
    o.x = f2bf(tile[cc + 0][rr]); o.y = f2bf(tile[cc + 1][rr]);
    o.z = f2bf(tile[cc + 2][rr]); o.w = f2bf(tile[cc + 3][rr]);
    *(ushort4*)(dst + (size_t)(tc0 + rr) * R + tr0 + cc) = o;
  }
}

// ---------------------------------------------------------------------------
// K4: coarse scores = cn[k] - 2 * (xq . cq) via MX-fp8 MFMA (K=128).
// 128x128 tile, 4 waves (2x2), 8 K-tiles, single-buffer LDS 32KB (frozen).
// R13: L2-blocked traversal -- per XCD (16 mb x 64 nb), iterate in
// 4mb x 8nb chunks (working set 1.5MB < 4MB L2). Bijective.
// Fold: packed keys -> LDS transpose 2-phase -> cand2[row][nb] top-2 keys.
// ---------------------------------------------------------------------------
__global__ __launch_bounds__(256, 3) void coarse_kernel(
    const uint8_t* __restrict__ xq,   // [MROWS][DDIM] fp8
    const uint8_t* __restrict__ cq,   // [KCODES][DDIM] fp8
    const float* __restrict__ cn,     // [KCODES]
    uint32_t* __restrict__ cand2)     // [MROWS][64][2] keys
{
  __shared__ char smem[34816];   // main: 32KB (A16+B16); fold: 128x34 uint2

  const int tid = threadIdx.x;
  const int l = tid & 63, w = tid >> 6;
  const int lr = l & 15, lg = l >> 4;
  const int wm = w >> 1, wn = w & 1;

  // XCD assignment + L2-blocked order within XCD (4mb x 8nb chunks)
  const int bid = blockIdx.x;
  const int xcd = bid & 7;
  const int local = bid >> 3;            // 0..1023
  const int chunk = local >> 5;          // 0..31
  const int wi = local & 31;             // 0..31
  const int mb = xcd * 16 + (chunk >> 3) * 4 + (wi >> 3);   // 0..127
  const int nb = (chunk & 7) * 8 + (wi & 7);                // 0..63
  const int r0 = mb * 128, c0 = nb * 128;

  const int scolb = ((tid & 7) * 16) ^ (((tid >> 3) & 7) << 4);
  const uint8_t* aSrc = xq + (size_t)(r0 + (tid >> 3)) * DDIM + scolb;
  const uint8_t* bSrc = cq + (size_t)(c0 + (tid >> 3)) * DDIM + scolb;
  const int dBase = tid * 16;

  const int sxor = (lr & 7) << 4;
  const int kLo = (lg * 32) ^ sxor;
  const int kHi = (lg * 32 + 16) ^ sxor;
  const int aRow = (wm * 64 + lr) * 128;            // + mi*2048
  const int bRow = 16384 + (wn * 64 + lr) * 128;    // + ni*2048

#define STAGE(KT)                                                             \
  {                                                                           \
    _Pragma("unroll")                                                         \
    for (int j = 0; j < 4; ++j)                                               \
      gload_lds16(aSrc + (size_t)j * 32 * DDIM + (KT) * 128,                  \
                  smem + dBase + j * 4096);                                   \
    _Pragma("unroll")                                                         \
    for (int j = 0; j < 4; ++j)                                               \
      gload_lds16(bSrc + (size_t)j * 32 * DDIM + (KT) * 128,                  \
                  smem + 16384 + dBase + j * 4096);                           \
  }

#define LDFRAG(dst, off)                                                      \
  {                                                                           \
    i32x4 _lo = *(const i32x4*)(smem + (off) + kLo);                          \
    i32x4 _hi = *(const i32x4*)(smem + (off) + kHi);                          \
    dst = __builtin_shufflevector(_lo, _hi, 0, 1, 2, 3, 4, 5, 6, 7);          \
  }

  f32x4 acc[4][4];
#pragma unroll
  for (int mi = 0; mi < 4; ++mi)
#pragma unroll
    for (int ni = 0; ni < 4; ++ni) acc[mi][ni] = 0.0f;

#pragma unroll 1
  for (int kt = 0; kt < 8; ++kt) {
    __builtin_amdgcn_sched_barrier(0);
    STAGE(kt)
    __builtin_amdgcn_sched_barrier(0);
    __syncthreads();                        // loads landed (vmcnt drained)

    i32x8 bf[4];
#pragma unroll
    for (int ni = 0; ni < 4; ++ni) LDFRAG(bf[ni], bRow + ni * 2048)
#pragma unroll
    for (int mi = 0; mi < 4; ++mi) {
      i32x8 af;
      LDFRAG(af, aRow + mi * 2048)
      __builtin_amdgcn_s_setprio(1);
#pragma unroll
      for (int ni = 0; ni < 4; ++ni)
        acc[mi][ni] = mfma_mx(af, bf[ni], acc[mi][ni]);
      __builtin_amdgcn_s_setprio(0);
    }

    __builtin_amdgcn_sched_barrier(0);      // no ds_read may sink below
    __syncthreads();                        // all reads done; buffer free
  }

  // ---- fold phase 1: per-lane key top-2 of 4 cols -> LDS [128][34] uint2 --
  uint2* mrg = (uint2*)smem;
  const int slot = wn * 16 + lr;

  float cnv[4];
#pragma unroll
  for (int ni = 0; ni < 4; ++ni) cnv[ni] = cn[c0 + wn * 64 + ni * 16 + lr];

#pragma unroll
  for (int mi = 0; mi < 4; ++mi) {
#pragma unroll
    for (int r = 0; r < 4; ++r) {
      uint32_t k1 = 0xFFFFFFFFu, k2 = 0xFFFFFFFFu;
#pragma unroll
      for (int ni = 0; ni < 4; ++ni) {
        const float s = fmaf(-2.0f, acc[mi][ni][r], cnv[ni]);
        const uint32_t k = packkey(s, c0 + wn * 64 + ni * 16 + lr);
        if (k < k1) { k2 = k1; k1 = k; } else if (k < k2) { k2 = k; }
      }
      const int row = wm * 64 + mi * 16 + lg * 4 + r;
      uint2 e; e.x = k1; e.y = k2;
      mrg[row * 34 + slot] = e;
    }
  }
  __syncthreads();

  // ---- fold phase 2: (row, half) thread scans 32 keys, cross-half merge ---
  {
    const int row = tid >> 1, h = tid & 1;
    const uint4* mp = (const uint4*)(mrg + row * 34 + h * 16);
    uint32_t k1 = 0xFFFFFFFFu, k2 = 0xFFFFFFFFu;
#pragma unroll
    for (int j = 0; j < 8; ++j) {
      const uint4 v = mp[j];
      uint32_t a = (k1 < v.x) ? k1 : v.x;
      uint32_t b0 = (k1 < v.x) ? v.x : k1;
      uint32_t c = (k2 < v.y) ? k2 : v.y;
      k1 = a; k2 = (b0 < c) ? b0 : c;
      a = (k1 < v.z) ? k1 : v.z;
      b0 = (k1 < v.z) ? v.z : k1;
      c = (k2 < v.w) ? k2 : v.w;
      k1 = a; k2 = (b0 < c) ? b0 : c;
    }
    const uint32_t o1 = (uint32_t)__shfl_xor((int)k1, 1, 64);
    const uint32_t o2 = (uint32_t)__shfl_xor((int)k2, 1, 64);
    const uint32_t m1 = (k1 < o1) ? k1 : o1;
    const uint32_t hi = (k1 < o1) ? o1 : k1;
    const uint32_t lo2 = (k2 < o2) ? k2 : o2;
    const uint32_t m2 = (hi < lo2) ? hi : lo2;
    if (h == 0) {
      uint2 o; o.x = m1; o.y = m2;
      *((uint2*)(cand2 + ((size_t)(r0 + row) * 64 + nb) * 2)) = o;
    }
  }
#undef STAGE
#undef LDFRAG
}

// ---------------------------------------------------------------------------
// K5: top-select + exact fp32 rescore on packed keys (frozen from R11).
// ---------------------------------------------------------------------------
__global__ __launch_bounds__(256) void rescore_kernel(
    const float* __restrict__ x, const float* __restrict__ cb,
    const uint32_t* __restrict__ cand2, int* __restrict__ idx_ws,
    float* __restrict__ out) {
  const int row = blockIdx.x * 4 + (threadIdx.x >> 6);
  const int l = threadIdx.x & 63;

  const uint2 pr = ((const uint2*)cand2)[(size_t)row * 64 + l];
  const uint32_t k1 = pr.x, k2 = pr.y;

  uint32_t bs = k1;
#pragma unroll
  for (int off = 1; off < 64; off <<= 1) {
    const uint32_t ob = (uint32_t)__shfl_xor((int)bs, off, 64);
    bs = (ob < bs) ? ob : bs;
  }
  const float smin = unpackkey(bs);
  const uint32_t thrkey = packkey(smin + 36.0f, 8191);
  unsigned long long mA = __ballot(k1 <= thrkey);
  unsigned long long mB = __ballot(k2 <= thrkey);

  if (__popcll(mA) + __popcll(mB) == 1) {
    if (l == 0) {
      const int code = (int)(bs & 8191u);
      idx_ws[row] = code;
      out[(size_t)MROWS * DDIM + row] = (float)code;
    }
    return;
  }

  const float4* x4 = (const float4*)(x + (size_t)row * DDIM);
  float4 xv[4];
#pragma unroll
  for (int i = 0; i < 4; ++i) xv[i] = x4[i * 64 + l];

  float bestS = __builtin_inff(); int bestI = KCODES;
#pragma unroll 1
  for (int half = 0; half < 2; ++half) {
    unsigned long long m = half ? mB : mA;
    const uint32_t myk = half ? k2 : k1;
    while (m) {
      const int b = __builtin_ctzll(m);
      m &= m - 1;
      const int code = __shfl((int)myk, b, 64) & 8191;
      const float4* c4 = (const float4*)(cb + (size_t)code * DDIM);
      float dot = 0.f, nn = 0.f;
#pragma unroll
      for (int i = 0; i < 4; ++i) {
        const float4 cv = c4[i * 64 + l];
        dot = fmaf(xv[i].x, cv.x, dot); dot = fmaf(xv[i].y, cv.y, dot);
        dot = fmaf(xv[i].z, cv.z, dot); dot = fmaf(xv[i].w, cv.w, dot);
        nn  = fmaf(cv.x, cv.x, nn);     nn  = fmaf(cv.y, cv.y, nn);
        nn  = fmaf(cv.z, cv.z, nn);     nn  = fmaf(cv.w, cv.w, nn);
      }
#pragma unroll
      for (int off = 32; off > 0; off >>= 1) {
        dot += __shfl_xor(dot, off, 64);
        nn  += __shfl_xor(nn,  off, 64);
      }
      const float sc = nn - 2.0f * dot;
      if (sc < bestS || (sc == bestS && code < bestI)) { bestS = sc; bestI = code; }
    }
  }
  if (l == 0) {
    idx_ws[row] = bestI;
    out[(size_t)MROWS * DDIM + row] = (float)bestI;
  }
}

// ---------------------------------------------------------------------------
// K6/K7: bf16 GEMM C = A[M][K] * B[N][K]^T (+bias). EPI==1: relu->bf16.
// EPI==2: f32 store. (Frozen.)
// ---------------------------------------------------------------------------
template <int EPI>
__global__ __launch_bounds__(256) void gemm_bt_kernel(
    const unsigned short* __restrict__ A, const unsigned short* __restrict__ B,
    const float* __restrict__ bias, void* __restrict__ outp,
    int Nsize, int Kred, int nblk) {
  __shared__ unsigned short As[128 * 32];
  __shared__ unsigned short Bs[128 * 32];
  const int tid = threadIdx.x;
  const int l = tid & 63, w = tid >> 6;
  const int lr = l & 15, lg = l >> 4;
  const int wm = w >> 1, wn = w & 1;
  const int mb = blockIdx.x / nblk, nb = blockIdx.x % nblk;
  const int r0 = mb * 128, c0 = nb * 128;
  const int prow = tid >> 2, pcol = (tid & 3) * 8;

  f32x4 acc[4][4];
#pragma unroll
  for (int mi = 0; mi < 4; ++mi)
#pragma unroll
    for (int ni = 0; ni < 4; ++ni) acc[mi][ni] = 0.0f;

  const size_t aoff0 = (size_t)(r0 + prow) * Kred + pcol;
  const size_t aoff1 = aoff0 + (size_t)64 * Kred;
  const size_t boff0 = (size_t)(c0 + prow) * Kred + pcol;
  const size_t boff1 = boff0 + (size_t)64 * Kred;

  const int nks = Kred >> 5;
  for (int ks = 0; ks < nks; ++ks) {
    const int k0 = ks * 32;
    gload_lds16(A + aoff0 + k0, &As[tid * 8]);
    gload_lds16(A + aoff1 + k0, &As[2048 + tid * 8]);
    gload_lds16(B + boff0 + k0, &Bs[tid * 8]);
    gload_lds16(B + boff1 + k0, &Bs[2048 + tid * 8]);
    __syncthreads();

    bf16x8 af[4], bfv[4];
#pragma unroll
    for (int mi = 0; mi < 4; ++mi)
      af[mi] = *reinterpret_cast<const bf16x8*>(
          &As[(wm * 64 + mi * 16 + lr) * 32 + lg * 8]);
#pragma unroll
    for (int ni = 0; ni < 4; ++ni)
      bfv[ni] = *reinterpret_cast<const bf16x8*>(
          &Bs[(wn * 64 + ni * 16 + lr) * 32 + lg * 8]);
#pragma unroll
    for (int mi = 0; mi < 4; ++mi)
#pragma unroll
      for (int ni = 0; ni < 4; ++ni)
        acc[mi][ni] = __builtin_amdgcn_mfma_f32_16x16x32_bf16(
            af[mi], bfv[ni], acc[mi][ni], 0, 0, 0);
    __syncthreads();
  }

#pragma unroll
  for (int ni = 0; ni < 4; ++ni) {
    const int col = c0 + wn * 64 + ni * 16 + lr;
    const float bv = bias[col];
#pragma unroll
    for (int mi = 0; mi < 4; ++mi) {
#pragma unroll
      for (int r = 0; r < 4; ++r) {
        const int row = r0 + wm * 64 + mi * 16 + lg * 4 + r;
        const float v = acc[mi][ni][r] + bv;
        if (EPI == 1) {
          ((unsigned short*)outp)[(size_t)row * Nsize + col] =
              f2bf(fmaxf(v, 0.0f));
        } else {
          ((float*)outp)[(size_t)row * Nsize + col] = v;
        }
      }
    }
  }
}

// ---------------------------------------------------------------------------
// K8: recon gather + loss partials. 16 rows/block (ILP); per-block partial
// to ws (no global atomics).
// ---------------------------------------------------------------------------
__global__ __launch_bounds__(256) void epilogue_kernel(
    const float* __restrict__ x, const float* __restrict__ cb,
    const float* __restrict__ dec, const int* __restrict__ idx_ws,
    float* __restrict__ out, float* __restrict__ partial) {
  __shared__ float wsum[4];
  const int t = threadIdx.x;
  const int base = blockIdx.x * EROWS;

  int code[EROWS];
#pragma unroll
  for (int rr = 0; rr < EROWS; ++rr) code[rr] = idx_ws[base + rr];

  float lsum = 0.0f;
#pragma unroll
  for (int rr = 0; rr < EROWS; ++rr) {
    const int r = base + rr;
    const float4 dv = ((const float4*)(dec + (size_t)code[rr] * DDIM))[t];
    ((float4*)(out + (size_t)r * DDIM))[t] = dv;
    const float4 xv = ((const float4*)(x + (size_t)r * DDIM))[t];
    const float4 cv = ((const float4*)(cb + (size_t)code[rr] * DDIM))[t];
    const float ex = xv.x - cv.x, ey = xv.y - cv.y;
    const float ez = xv.z - cv.z, ew = xv.w - cv.w;
    lsum += ex * ex + ey * ey + ez * ez + ew * ew;
  }
  lsum = waveReduceSum(lsum);
  if ((t & 63) == 0) wsum[t >> 6] = lsum;
  __syncthreads();
  if (t == 0)
    partial[blockIdx.x] = wsum[0] + wsum[1] + wsum[2] + wsum[3];
}

// ---------------------------------------------------------------------------
// K9: deterministic final loss reduce over MROWS/EROWS (=1024) partials.
// ---------------------------------------------------------------------------
__global__ __launch_bounds__(256) void loss_reduce_kernel(
    const float* __restrict__ partial, float* __restrict__ out) {
  __shared__ float wsum[4];
  const int t = threadIdx.x;
  float s = 0.0f;
#pragma unroll
  for (int j = 0; j < 4; ++j) s += partial[t * 4 + j];
  s = waveReduceSum(s);
  if ((t & 63) == 0) wsum[t >> 6] = s;
  __syncthreads();
  if (t == 0) {
    const float total = wsum[0] + wsum[1] + wsum[2] + wsum[3];
    // 0.25 / 16777216 is a power-of-two scale: exact
    out[(size_t)MROWS * DDIM + MROWS] = total * (0.25f / 16777216.0f);
  }
}

// ---------------------------------------------------------------------------
extern "C" void kernel_launch(void* const* d_in, const int* in_sizes, int n_in,
                              void* d_out, int out_size, void* d_ws,
                              size_t ws_size, hipStream_t stream) {
  const float* features = (const float*)d_in[0];  // [8,2048,1024]
  const float* codebook = (const float*)d_in[1];  // [8192,1024]
  const float* w1 = (const float*)d_in[2];        // [1024,512]
  const float* b1 = (const float*)d_in[3];        // [512]
  const float* w2 = (const float*)d_in[4];        // [512,1024]
  const float* b2 = (const float*)d_in[5];        // [1024]
  float* out = (float*)d_out;
  char* ws = (char*)d_ws;

  uint8_t*        xq8 = (uint8_t*)(ws + 0);                // 16,777,216
  uint8_t*        cq8 = (uint8_t*)(ws + 16777216);         //  8,388,608
  unsigned short* cbb = (unsigned short*)(ws + 25165824);  // 16,777,216
  float*          cn  = (float*)(ws + 41943040);           //     32,768
  unsigned short* w1t = (unsigned short*)(ws + 41975808);  //  1,048,576
  unsigned short* w2t = (unsigned short*)(ws + 43024384);  //  1,048,576
  unsigned short* hb  = (unsigned short*)(ws + 44072960);  //  8,388,608
  float*          dec = (float*)(ws + 52461568);           // 33,554,432
  int*            idxw = (int*)(ws + 86016000);            //     65,536
  float*          lpart = (float*)(ws + 86081536);         //      8,192
  // cand2 (8 MB) aliases dec: consumed by rescore BEFORE gemm<2> writes dec
  // (stream-ordered -> safe).
  uint32_t*       cand2 = (uint32_t*)(ws + 52461568);

  prep_kernel<<<17408, 256, 0, stream>>>(features, codebook, w1, w2,
                                         xq8, cq8, cbb, cn, w1t, w2t);

  coarse_kernel<<<(MROWS / 128) * (KCODES / 128), 256, 0, stream>>>(
      xq8, cq8, cn, cand2);
  rescore_kernel<<<MROWS / 4, 256, 0, stream>>>(features, codebook, cand2,
                                                idxw, out);

  // decode the codebook (8192 rows), then recon = dec[idx]
  gemm_bt_kernel<1><<<64 * (HDIM / 128), 256, 0, stream>>>(
      cbb, w1t, b1, hb, HDIM, DDIM, HDIM / 128);
  gemm_bt_kernel<2><<<64 * (DDIM / 128), 256, 0, stream>>>(
      hb, w2t, b2, dec, DDIM, HDIM, DDIM / 128);

  epilogue_kernel<<<MROWS / EROWS, 256, 0, stream>>>(features, codebook, dec,
                                                     idxw, out, lpart);
  loss_reduce_kernel<<<1, 256, 0, stream>>>(lpart, out);
}